// Round 12
// baseline (224853.052 us; speedup 1.0000x reference)
//
#include <hip/hip_runtime.h>
#include <hip/hip_fp16.h>
#include <math.h>

#define TENC 400
#define TMEL 800
#define NMEL 80
#define ENCD 768
#define PRE  256
#define ARNN 1024
#define DRNN 1024
#define ATTD 128
#define NBLK 256

typedef unsigned uint32;

__device__ __forceinline__ float4 ld4(const float* p){ return *(const float4*)p; }
__device__ __forceinline__ float dot4(float4 a, float4 b){
  return a.x*b.x + a.y*b.y + a.z*b.z + a.w*b.w;
}
__device__ __forceinline__ float sigmf(float x){ return 1.f/(1.f + __expf(-x)); }

// =================== fenced tree grid barrier (r10-proven semantics) ===================
__device__ __forceinline__ void gbar(uint32* bar, uint32 phase, int bk)
{
  __syncthreads();
  if (threadIdx.x == 0) {
    __builtin_amdgcn_fence(__ATOMIC_RELEASE, "agent");   // writeback L2
    uint32* leaf = bar + (bk & 7) * 32;
    uint32* root = bar + 256;
    uint32* rel  = bar + 288;
    uint32 a = __hip_atomic_fetch_add(leaf, 1u, __ATOMIC_RELAXED,
                                      __HIP_MEMORY_SCOPE_AGENT) + 1u;
    if (a == phase * 32u) {
      uint32 r = __hip_atomic_fetch_add(root, 1u, __ATOMIC_RELAXED,
                                        __HIP_MEMORY_SCOPE_AGENT) + 1u;
      if (r == phase * 8u)
        __hip_atomic_store(rel, phase, __ATOMIC_RELAXED, __HIP_MEMORY_SCOPE_AGENT);
    }
    while (__hip_atomic_load(rel, __ATOMIC_RELAXED, __HIP_MEMORY_SCOPE_AGENT) < phase)
      __builtin_amdgcn_s_sleep(8);
    __builtin_amdgcn_fence(__ATOMIC_ACQUIRE, "agent");   // invalidate L2
  }
  __syncthreads();
}

// =================== prenet: xsT[t][k=256][b=32] ===================
__global__ __launch_bounds__(256) void prenet_kernel(
    const float* __restrict__ din, const float* __restrict__ w1,
    const float* __restrict__ w2, float* __restrict__ xsT)
{
  int t = blockIdx.x;
  __shared__ float f_s[32*80];
  __shared__ float p_s[32*257];
  for (int id = threadIdx.x; id < 32*80; id += 256) {
    int b = id / 80, m = id - b*80;
    f_s[id] = (t == 0) ? 0.f : din[b*(NMEL*TMEL) + m*TMEL + (t-1)];
  }
  __syncthreads();
  for (int b = 0; b < 32; ++b) {
    int k = threadIdx.x;
    float acc = 0.f;
    #pragma unroll 4
    for (int m = 0; m < 80; ++m) acc += f_s[b*80+m] * w1[k*80+m];
    p_s[b*257+k] = fmaxf(acc, 0.f);
  }
  __syncthreads();
  int b = threadIdx.x & 31, jslot = threadIdx.x >> 5;
  for (int jj = 0; jj < 32; ++jj) {
    int j = jslot*32 + jj;
    const float* w2r = w2 + j*256;
    float acc = 0.f;
    #pragma unroll 4
    for (int kk = 0; kk < 256; ++kk) acc += p_s[b*257+kk] * w2r[kk];
    xsT[(size_t)t*8192 + j*32 + b] = fmaxf(acc, 0.f);
  }
}

// =================== pmem16[b][t][128] (fp16) ===================
__global__ __launch_bounds__(256) void pmem_kernel(
  const float* __restrict__ mem, const float* __restrict__ mw, __half* __restrict__ pm16)
{
  int b = blockIdx.y, tc = blockIdx.x;
  int a = threadIdx.x & 127, th = threadIdx.x >> 7;
  for (int i = 0; i < 8; ++i) {
    int tt = tc*16 + th + 2*i;
    const float* mrow = mem + (size_t)b*(TENC*ENCD) + (size_t)tt*ENCD;
    const float* wrow = mw + a*ENCD;
    float acc = 0.f;
    #pragma unroll 4
    for (int e4 = 0; e4 < ENCD; e4 += 4) acc += dot4(ld4(mrow+e4), ld4(wrow+e4));
    pm16[b*(TENC*ATTD) + tt*ATTD + a] = __float2half(acc);
  }
}

// =================== fp32 -> fp16 convert ===================
__global__ __launch_bounds__(256) void cvt16_kernel(
  const float* __restrict__ src, __half* __restrict__ dst, int n)
{
  int i = blockIdx.x*256 + threadIdx.x;
  int st = gridDim.x*256;
  for (; i < n; i += st) dst[i] = __float2half(src[i]);
}

// =================== args struct ===================
struct DecArgs {
  const float *xsT;
  const __half *awih16, *awhh16, *dwih16, *dwhh16, *qw16, *pm16;
  const float *abih, *abhh, *dbih, *dbhh;
  const float *cw, *ldw, *vw;
  const int*  mlen;
  const float *pw, *pb, *gw, *gb;
  float *ahT, *acT, *dhT, *dh, *dcT, *ah_row;
  float *ctxT, *ctx2, *aw, *awcb, *e;
  const float *memory;
  float *out_mel, *out_gate, *out_align;
  uint32 *bar;
};

// =================== register-weight GEMM machinery ===================
// Thread (rg = tid>>5, kid = tid&31): rows {2rg, 2rg+1}, k-slice kid*8..+8 per chunk.
// Weights fp16 in VGPRs (uint-packed half2). X streams via LDS fp32 dbuf chunks.

template<int NC, int KIHC, int KIH>
__device__ __forceinline__ void load_w(uint32* w0, uint32* w1,
  const __half* __restrict__ wih, const __half* __restrict__ whh,
  int u0, int rg, int kid)
{
  #pragma unroll
  for (int i = 0; i < 2; ++i) {
    int r = rg*2 + i;
    int j = (r>>2)*1024 + u0 + (r&3);
    uint32* wd = i ? w1 : w0;
    #pragma unroll
    for (int c = 0; c < NC; ++c) {
      const __half* src = (c < KIHC) ? (wih + (size_t)j*KIH  + c*256 + kid*8)
                                     : (whh + (size_t)j*1024 + (c-KIHC)*256 + kid*8);
      uint4 v = *(const uint4*)src;
      wd[c*4+0]=v.x; wd[c*4+1]=v.y; wd[c*4+2]=v.z; wd[c*4+3]=v.w;
    }
  }
}

__device__ __forceinline__ void stage_chunk(const float* __restrict__ src,
                                            float* __restrict__ Xb, int tid)
{
  int col = tid & 7;
  int kr0 = tid >> 3;
  #pragma unroll
  for (int i = 0; i < 8; ++i) {
    int kr = kr0 + i*32;
    int swz = ((kr>>3) + (kr>>6)) & 7;
    float4 v = *(const float4*)(src + (size_t)kr*32 + col*4);
    *(float4*)(Xb + kr*32 + (((col ^ swz))<<2)) = v;
  }
}

__device__ __forceinline__ void comp_chunk(const float* __restrict__ Xb,
  const uint32* w0, const uint32* w1, float* acc0, float* acc1, int kid, int swzr)
{
  const float4* X4 = (const float4*)Xb;
  #pragma unroll
  for (int kq = 0; kq < 4; ++kq) {
    float2 wf0 = __half22float2(*(const __half2*)&w0[kq]);
    float2 wf1 = __half22float2(*(const __half2*)&w1[kq]);
    #pragma unroll
    for (int h = 0; h < 2; ++h) {
      int krow = kid*8 + kq*2 + h;
      float wk0 = h ? wf0.y : wf0.x;
      float wk1 = h ? wf1.y : wf1.x;
      #pragma unroll
      for (int s = 0; s < 8; ++s) {
        float4 xv = X4[krow*8 + (s ^ swzr)];
        acc0[s*4+0] += wk0*xv.x; acc0[s*4+1] += wk0*xv.y;
        acc0[s*4+2] += wk0*xv.z; acc0[s*4+3] += wk0*xv.w;
        acc1[s*4+0] += wk1*xv.x; acc1[s*4+1] += wk1*xv.y;
        acc1[s*4+2] += wk1*xv.z; acc1[s*4+3] += wk1*xv.w;
      }
    }
  }
}

template<int NC>
__device__ __forceinline__ void gemm_body(const float* const* srcs,
  const uint32* w0, const uint32* w1, float* Xbuf, float* G,
  int tid, int rg, int kid, float* acc0, float* acc1)
{
  #pragma unroll
  for (int b = 0; b < 32; ++b){ acc0[b]=0.f; acc1[b]=0.f; }
  const int swzr = (kid + (kid>>3)) & 7;
  stage_chunk(srcs[0], Xbuf, tid);
  __syncthreads();
  #pragma unroll
  for (int c = 0; c < NC; ++c) {
    if (c+1 < NC) stage_chunk(srcs[c+1], Xbuf + ((c+1)&1)*8192, tid);
    comp_chunk(Xbuf + (c&1)*8192, w0 + c*4, w1 + c*4, acc0, acc1, kid, swzr);
    __syncthreads();
  }
  #pragma unroll
  for (int m = 16; m >= 1; m >>= 1) {
    #pragma unroll
    for (int b = 0; b < 32; ++b) {
      acc0[b] += __shfl_xor(acc0[b], m);
      acc1[b] += __shfl_xor(acc1[b], m);
    }
  }
  if (kid == 0) {
    int r0 = rg*2, r1 = rg*2+1;
    #pragma unroll
    for (int s = 0; s < 8; ++s) {
      *(float4*)(G + r0*32 + s*4) =
        make_float4(acc0[s*4],acc0[s*4+1],acc0[s*4+2],acc0[s*4+3]);
      *(float4*)(G + r1*32 + s*4) =
        make_float4(acc1[s*4],acc1[s*4+1],acc1[s*4+2],acc1[s*4+3]);
    }
  }
  __syncthreads();
}

// =================== LSTM cell tail (reads G) ===================
__device__ __forceinline__ void cell_tail(const float* G, int u0,
  const float* __restrict__ bih, const float* __restrict__ bhh,
  float* __restrict__ cT, float* __restrict__ hT_out, float* __restrict__ h_row,
  int tid)
{
  if (tid < 128) {
    int du = tid >> 5, b = tid & 31;
    int u = u0 + du;
    float gi = G[(0*4+du)*32 + b] + bih[u]      + bhh[u];
    float gf = G[(1*4+du)*32 + b] + bih[1024+u] + bhh[1024+u];
    float gg = G[(2*4+du)*32 + b] + bih[2048+u] + bhh[2048+u];
    float go = G[(3*4+du)*32 + b] + bih[3072+u] + bhh[3072+u];
    float c  = cT[u*32 + b];
    float cn = sigmf(gf)*c + sigmf(gi)*tanhf(gg);
    float h  = sigmf(go)*tanhf(cn);
    cT[u*32 + b]     = cn;
    hT_out[u*32 + b] = h;
    if (h_row) h_row[b*1024 + u] = h;
  }
  __syncthreads();
}

// =================== projection helper (plain cached loads) ===================
__device__ __forceinline__ void proj_task(int d, const float* dh, const float* ctx,
    const float* proj_w, const float* proj_b, const float* gate_w, const float* gate_b,
    float* out_mel, float* out_gate, int t)
{
  if (d >= 32*81) return;
  int b = d / 81, r = d - b*81;
  const float* w   = (r < 80) ? (proj_w + r*1792) : gate_w;
  const float* dhr = dh + b*DRNN;
  const float* cxr = ctx + b*ENCD;
  float acc = 0.f;
  #pragma unroll 4
  for (int k = 0; k < 1024; k += 4) acc += dot4(ld4(dhr+k), ld4(w+k));
  #pragma unroll 4
  for (int k = 0; k < 768;  k += 4) acc += dot4(ld4(cxr+k), ld4(w+1024+k));
  if (r < 80) out_mel[(b*80 + r)*TMEL + t] = acc + proj_b[r];
  else        out_gate[b*TMEL + t]         = acc + gate_b[0];
}

// =================== P2: energies (+ folded pq), plain loads ===================
__device__ __forceinline__ void energies_phase(int bk, const DecArgs& p,
  const float* awc_old, float* smem)
{
  int b = bk >> 3, c8 = bk & 7, t0 = c8 * 50;
  float* ah_s  = smem;          // 1024
  float* pq_s  = smem + 1024;   // 128
  float* part  = smem + 1152;   // 256
  float* aw_s  = smem + 1408;   // 80
  float* awc_s = smem + 1488;   // 80
  float* loc_s = smem + 1568;   // 50*33
  float* epart = smem + 3218;   // 50*4
  int tid = threadIdx.x;
  {
    float4 v = ld4(p.ah_row + b*1024 + tid*4);
    ah_s[tid*4] = v.x; ah_s[tid*4+1] = v.y; ah_s[tid*4+2] = v.z; ah_s[tid*4+3] = v.w;
  }
  if (tid >= 96) {              // halo: 160 threads -> i in [0,160)
    int i = tid - 96;
    int h = (i < 80) ? i : i - 80;
    bool isC = i >= 80;
    int g = t0 - 15 + h;
    float v = (g >= 0 && g < TENC)
            ? (isC ? awc_old[b*TENC+g] : p.aw[b*TENC+g]) : 0.f;
    if (isC) awc_s[h] = v; else aw_s[h] = v;
  }
  __syncthreads();
  {
    int a = tid & 127, kh = tid >> 7;
    const __half* qr = p.qw16 + (size_t)a*1024 + kh*512;
    const float*  ar = ah_s + kh*512;
    float acc = 0.f;
    for (int k = 0; k < 512; k += 8) {
      uint4 hv = *(const uint4*)(qr + k);
      const __half2* h2 = (const __half2*)&hv;
      #pragma unroll
      for (int q = 0; q < 4; ++q) {
        float2 wf = __half22float2(h2[q]);
        acc += ar[k + q*2]*wf.x + ar[k + q*2 + 1]*wf.y;
      }
    }
    part[tid] = acc;
  }
  __syncthreads();
  if (tid < 128) pq_s[tid] = part[tid] + part[tid + 128];
  for (int id = tid; id < 50*32; id += 256) {
    int tl = id >> 5, f = id & 31;
    const float* w0 = p.cw + f*62;
    float acc = 0.f;
    #pragma unroll
    for (int k = 0; k < 31; ++k)
      acc += aw_s[tl+k]*w0[k] + awc_s[tl+k]*w0[31+k];
    loc_s[tl*33 + f] = acc;
  }
  __syncthreads();
  if (tid < 200) {
    int tl = tid >> 2, qa = tid & 3;
    int tt = t0 + tl;
    const __half* pm = p.pm16 + b*(TENC*ATTD) + tt*ATTD;
    float s = 0.f;
    for (int a = qa*32; a < qa*32 + 32; ++a) {
      const float* lw = p.ldw + a*32;
      float pl = 0.f;
      #pragma unroll 8
      for (int f = 0; f < 32; ++f) pl += loc_s[tl*33 + f] * lw[f];
      s += p.vw[a] * tanhf(pq_s[a] + __half2float(pm[a]) + pl);
    }
    epart[tl*4 + qa] = s;
  }
  __syncthreads();
  if (tid < 50) {
    int tt = t0 + tid;
    float v = epart[tid*4] + epart[tid*4+1] + epart[tid*4+2] + epart[tid*4+3];
    if (tt >= p.mlen[b]) v = -1000000000.0f;
    p.e[b*TENC + tt] = v;
  }
  __syncthreads();
}

// =================== P3: softmax + LDS-resident ctx ===================
__device__ __forceinline__ void sm_ctx_phase(int bk, int t, const DecArgs& p,
  const float* awc_old, float* awc_new, float* ctx_cur, const __half2* mem_s,
  float* smem)
{
  int b = bk >> 3, jc = bk & 7, j0 = jc*96;
  int tid = threadIdx.x;
  float* red   = smem;         // 256
  float* aw_s  = smem + 256;   // 400
  float* cpart = smem + 656;   // 384
  float v0 = p.e[b*TENC + tid];
  float v1 = (tid + 256 < TENC) ? p.e[b*TENC + tid + 256] : -3.0e38f;
  red[tid] = fmaxf(v0, v1); __syncthreads();
  for (int s = 128; s > 0; s >>= 1) {
    if (tid < s) red[tid] = fmaxf(red[tid], red[tid+s]);
    __syncthreads();
  }
  float mx = red[0]; __syncthreads();
  float p0 = __expf(v0 - mx);
  float p1 = (tid + 256 < TENC) ? __expf(v1 - mx) : 0.f;
  red[tid] = p0 + p1; __syncthreads();
  for (int s = 128; s > 0; s >>= 1) {
    if (tid < s) red[tid] += red[tid+s];
    __syncthreads();
  }
  float inv = 1.f / red[0];
  aw_s[tid] = p0 * inv;
  if (tid + 256 < TENC) aw_s[tid + 256] = p1 * inv;
  __syncthreads();
  if (tid < 192) {
    int jp = tid % 48, h = tid / 48;
    float ax = 0.f, ay = 0.f;
    for (int tt = h*100; tt < h*100 + 100; ++tt) {
      float av = aw_s[tt];
      float2 m = __half22float2(mem_s[tt*48 + jp]);
      ax += av * m.x; ay += av * m.y;
    }
    cpart[(h*48 + jp)*2]     = ax;
    cpart[(h*48 + jp)*2 + 1] = ay;
  }
  __syncthreads();
  if (tid < 48) {
    float sx = cpart[tid*2]        + cpart[(48+tid)*2]
             + cpart[(96+tid)*2]   + cpart[(144+tid)*2];
    float sy = cpart[tid*2+1]      + cpart[(48+tid)*2+1]
             + cpart[(96+tid)*2+1] + cpart[(144+tid)*2+1];
    int j = j0 + tid*2;
    p.ctxT[(size_t)j*32 + b]     = sx;
    p.ctxT[(size_t)(j+1)*32 + b] = sy;
    ctx_cur[b*ENCD + j]     = sx;
    ctx_cur[b*ENCD + j + 1] = sy;
  }
  if (jc == 0) {
    for (int i = tid; i < TENC; i += 256) {
      float a = aw_s[i];
      p.aw[b*TENC + i] = a;
      awc_new[b*TENC + i] = awc_old[b*TENC + i] + a;
      p.out_align[((size_t)b*TMEL + t)*TENC + i] = a;
    }
  }
  __syncthreads();
}

// =================== THE persistent kernel ===================
__global__ __launch_bounds__(256, 1) void decoder_loop(DecArgs p)
{
  __shared__ __align__(16) float smem[16896];   // X dbuf 2x8192 + G 512 = 67.6 KB
  __shared__ __half2 mem_s[400*48];             // 76.8 KB persistent
  float* G = smem + 16384;
  const int bk = blockIdx.x, tid = threadIdx.x;
  const int u0 = bk * 4;
  const int rg = tid >> 5, kid = tid & 31;
  uint32 phase = 0;

  // ---- weights -> registers (held live across all 800 steps) ----
  uint32 wa0[32], wa1[32], wd0[44], wd1[44];
  load_w<8, 4, 1024>(wa0, wa1, p.awih16, p.awhh16, u0, rg, kid);
  load_w<11, 7, 1792>(wd0, wd1, p.dwih16, p.dwhh16, u0, rg, kid);

  { // preload memory slice (immutable)
    int b = bk >> 3, jc = bk & 7, j0 = jc*96;
    const float* mb = p.memory + (size_t)b*(TENC*ENCD);
    for (int idx = tid; idx < 400*48; idx += 256) {
      int tt = idx / 48, jp = idx - tt*48;
      float m0 = mb[(size_t)tt*ENCD + j0 + jp*2];
      float m1 = mb[(size_t)tt*ENCD + j0 + jp*2 + 1];
      mem_s[idx] = __floats2half2_rn(m0, m1);
    }
  }
  __syncthreads();

  float acc0[32], acc1[32];

  for (int t = 0; t < TMEL; ++t) {
    const float* ahT_rd  = p.ahT  + ((t+1)&1)*32768;
    float*       ahT_wr  = p.ahT  + (t&1)*32768;
    const float* dhT_rd  = p.dhT  + ((t+1)&1)*32768;
    float*       dhT_wr  = p.dhT  + (t&1)*32768;
    const float* awc_old = p.awcb + ((t+1)&1)*12800;
    float*       awc_new = p.awcb + (t&1)*12800;
    float*       ctx_cur = p.ctx2 + (t&1)*24576;
    const float* ctx_prev= p.ctx2 + ((t+1)&1)*24576;

    // P1: att-GEMM (reg weights) + cell
    {
      const float* xs = p.xsT + (size_t)t*8192;
      const float* srcs[8] = { xs,
        p.ctxT, p.ctxT + 8192, p.ctxT + 16384,
        ahT_rd, ahT_rd + 8192, ahT_rd + 16384, ahT_rd + 24576 };
      gemm_body<8>(srcs, wa0, wa1, smem, G, tid, rg, kid, acc0, acc1);
    }
    cell_tail(G, u0, p.abih, p.abhh, p.acT, ahT_wr, p.ah_row, tid);
    gbar(p.bar, ++phase, bk);

    // P2: energies (+pq)
    energies_phase(bk, p, awc_old, smem);
    gbar(p.bar, ++phase, bk);

    // P3: softmax + ctx + proj(t-1) on 16 blocks
    sm_ctx_phase(bk, t, p, awc_old, awc_new, ctx_cur, mem_s, smem);
    if ((bk & 7) == 7 && (bk >> 3) < 16 && t > 0) {
      int d = (bk >> 3)*256 + tid;
      proj_task(d, p.dh, ctx_prev, p.pw, p.pb, p.gw, p.gb,
                p.out_mel, p.out_gate, t-1);
    }
    gbar(p.bar, ++phase, bk);

    // P4: dec-GEMM (reg weights) + cell
    {
      const float* srcs[11] = {
        ahT_wr, ahT_wr + 8192, ahT_wr + 16384, ahT_wr + 24576,
        p.ctxT, p.ctxT + 8192, p.ctxT + 16384,
        dhT_rd, dhT_rd + 8192, dhT_rd + 16384, dhT_rd + 24576 };
      gemm_body<11>(srcs, wd0, wd1, smem, G, tid, rg, kid, acc0, acc1);
    }
    cell_tail(G, u0, p.dbih, p.dbhh, p.dcT, dhT_wr, p.dh, tid);
    gbar(p.bar, ++phase, bk);
  }

  // final projection (t = TMEL-1)
  if ((bk & 7) == 7 && (bk >> 3) < 16) {
    int d = (bk >> 3)*256 + tid;
    proj_task(d, p.dh, p.ctx2 + ((TMEL-1)&1)*24576, p.pw, p.pb, p.gw, p.gb,
              p.out_mel, p.out_gate, TMEL-1);
  }
}

extern "C" void kernel_launch(void* const* d_in, const int* in_sizes, int n_in,
                              void* d_out, int out_size, void* d_ws, size_t ws_size,
                              hipStream_t stream)
{
  const float* memory = (const float*)d_in[0];
  const float* din    = (const float*)d_in[1];
  const float* w1     = (const float*)d_in[3];
  const float* w2     = (const float*)d_in[4];
  const float* awih   = (const float*)d_in[5];
  const float* awhh   = (const float*)d_in[6];
  const float* abih   = (const float*)d_in[7];
  const float* abhh   = (const float*)d_in[8];
  const float* q_w    = (const float*)d_in[9];
  const float* mem_w  = (const float*)d_in[10];
  const float* v_w    = (const float*)d_in[11];
  const float* cw     = (const float*)d_in[12];
  const float* ldw    = (const float*)d_in[13];
  const float* dwih   = (const float*)d_in[14];
  const float* dwhh   = (const float*)d_in[15];
  const float* dbih   = (const float*)d_in[16];
  const float* dbhh   = (const float*)d_in[17];
  const float* pw     = (const float*)d_in[18];
  const float* pb     = (const float*)d_in[19];
  const float* gw     = (const float*)d_in[20];
  const float* gb     = (const float*)d_in[21];
  const int*   mlen   = (const int*)d_in[22];

  float* p = (float*)d_ws;
  float* xsT    = p;              p += 800*256*32;
  __half* awih16 = (__half*)p;    p += 2097152;
  __half* awhh16 = (__half*)p;    p += 2097152;
  __half* dwih16 = (__half*)p;    p += 3670016;
  __half* dwhh16 = (__half*)p;    p += 2097152;
  __half* qw16   = (__half*)p;    p += 65536;
  __half* pm16   = (__half*)p;    p += 819200;
  // ---- zeroed state block ----
  float* zs    = p;
  uint32* bar  = (uint32*)p;      p += 320;
  float* ahT   = p;  p += 2*1024*32;
  float* dhT   = p;  p += 2*1024*32;
  float* dh    = p;  p += 32*1024;
  float* ah_row= p;  p += 32*1024;
  float* ctxT  = p;  p += 768*32;
  float* ctx2  = p;  p += 2*32*768;
  float* acT   = p;  p += 1024*32;
  float* dcT   = p;  p += 1024*32;
  float* aw    = p;  p += 32*400;
  float* awcb  = p;  p += 2*32*400;
  size_t zcount = (size_t)(p - zs);
  // ---- end zero block ----
  float* e     = p;  p += 32*400;

  float* out_mel   = (float*)d_out;
  float* out_gate  = out_mel + 32*80*800;
  float* out_align = out_gate + 32*800;

  hipMemsetAsync(zs, 0, zcount*sizeof(float), stream);
  prenet_kernel<<<TMEL, 256, 0, stream>>>(din, w1, w2, xsT);
  pmem_kernel<<<dim3(25,32), 256, 0, stream>>>(memory, mem_w, pm16);
  cvt16_kernel<<<256, 256, 0, stream>>>(q_w, qw16, 128*1024);
  cvt16_kernel<<<2048, 256, 0, stream>>>(awih, awih16, 4096*1024);
  cvt16_kernel<<<2048, 256, 0, stream>>>(awhh, awhh16, 4096*1024);
  cvt16_kernel<<<2048, 256, 0, stream>>>(dwih, dwih16, 4096*1792);
  cvt16_kernel<<<2048, 256, 0, stream>>>(dwhh, dwhh16, 4096*1024);

  DecArgs a;
  a.xsT = xsT;
  a.awih16 = awih16; a.awhh16 = awhh16; a.dwih16 = dwih16; a.dwhh16 = dwhh16;
  a.qw16 = qw16; a.pm16 = pm16;
  a.abih = abih; a.abhh = abhh; a.dbih = dbih; a.dbhh = dbhh;
  a.cw = cw; a.ldw = ldw; a.vw = v_w; a.mlen = mlen;
  a.pw = pw; a.pb = pb; a.gw = gw; a.gb = gb;
  a.ahT = ahT; a.acT = acT; a.dhT = dhT; a.dh = dh; a.dcT = dcT; a.ah_row = ah_row;
  a.ctxT = ctxT; a.ctx2 = ctx2; a.aw = aw; a.awcb = awcb; a.e = e;
  a.memory = memory;
  a.out_mel = out_mel; a.out_gate = out_gate; a.out_align = out_align;
  a.bar = bar;

  decoder_loop<<<NBLK, 256, 0, stream>>>(a);
}

// Round 13
// 182318.567 us; speedup vs baseline: 1.2333x; 1.2333x over previous
//
#include <hip/hip_runtime.h>
#include <hip/hip_fp16.h>
#include <math.h>

#define TENC 400
#define TMEL 800
#define NMEL 80
#define ENCD 768
#define PRE  256
#define ARNN 1024
#define DRNN 1024
#define ATTD 128
#define NBLK 256
#define SLOT 32   // 128B-padded barrier slots

typedef unsigned uint32;

__device__ __forceinline__ float4 ld4(const float* p){ return *(const float4*)p; }
__device__ __forceinline__ float dot4(float4 a, float4 b){
  return a.x*b.x + a.y*b.y + a.z*b.z + a.w*b.w;
}
__device__ __forceinline__ float sigmf(float x){ return 1.f/(1.f + __expf(-x)); }

// ---- coherent (agent-scope relaxed, cache-bypassing) accessors ----
__device__ __forceinline__ float ld_c(const float* p){
  union { unsigned u; float f; } c;
  c.u = __hip_atomic_load((const unsigned*)p, __ATOMIC_RELAXED, __HIP_MEMORY_SCOPE_AGENT);
  return c.f;
}
__device__ __forceinline__ void st_c(float* p, float v){
  union { unsigned u; float f; } c; c.f = v;
  __hip_atomic_store((unsigned*)p, c.u, __ATOMIC_RELAXED, __HIP_MEMORY_SCOPE_AGENT);
}
__device__ __forceinline__ float2 ld2_c(const float* p){
  union { unsigned long long u; float2 f; } c;
  c.u = __hip_atomic_load((const unsigned long long*)p, __ATOMIC_RELAXED,
                          __HIP_MEMORY_SCOPE_AGENT);
  return c.f;
}
__device__ __forceinline__ float4 ld4_c(const float* p){
  union { unsigned long long u[2]; float4 f; } c;
  c.u[0] = __hip_atomic_load((const unsigned long long*)p, __ATOMIC_RELAXED,
                             __HIP_MEMORY_SCOPE_AGENT);
  c.u[1] = __hip_atomic_load((const unsigned long long*)(p+2), __ATOMIC_RELAXED,
                             __HIP_MEMORY_SCOPE_AGENT);
  return c.f;
}
__device__ __forceinline__ uint32 ald(const uint32* p){
  return __hip_atomic_load(p, __ATOMIC_RELAXED, __HIP_MEMORY_SCOPE_AGENT);
}
__device__ __forceinline__ void ast(uint32* p, uint32 v){
  __hip_atomic_store(p, v, __ATOMIC_RELAXED, __HIP_MEMORY_SCOPE_AGENT);
}

// =================== contention-free grid barrier ===================
// Per-block padded arrive/release slots (monotonic phase). bk0's wave sweeps
// arrivals (4 slots/lane, pipelined independent lines) and fans out releases.
// No shared-line polling anywhere.
__device__ __forceinline__ void bar_grid(uint32* arr, uint32* rel, uint32 phase, int bk)
{
  __syncthreads();
  if (threadIdx.x < 64) {
    if (threadIdx.x == 0) {
      asm volatile("s_waitcnt vmcnt(0)" ::: "memory");   // drain coherent stores
      ast(arr + bk*SLOT, phase);
    }
    if (bk == 0) {
      int lane = threadIdx.x;
      for (;;) {
        uint32 m0 = ald(arr + (lane      )*SLOT);
        uint32 m1 = ald(arr + (lane +  64)*SLOT);
        uint32 m2 = ald(arr + (lane + 128)*SLOT);
        uint32 m3 = ald(arr + (lane + 192)*SLOT);
        bool ok = (m0 >= phase) & (m1 >= phase) & (m2 >= phase) & (m3 >= phase);
        if (__all(ok)) break;
        __builtin_amdgcn_s_sleep(1);
      }
      ast(rel + (threadIdx.x      )*SLOT, phase);
      ast(rel + (threadIdx.x +  64)*SLOT, phase);
      ast(rel + (threadIdx.x + 128)*SLOT, phase);
      ast(rel + (threadIdx.x + 192)*SLOT, phase);
    } else if (threadIdx.x == 0) {
      while (ald(rel + bk*SLOT) < phase) __builtin_amdgcn_s_sleep(1);
    }
  }
  __syncthreads();
}

// =================== 8-block group barrier (group g = bk>>3) ===================
__device__ __forceinline__ void bar_group(uint32* arr, uint32* rel, uint32 phase, int bk)
{
  __syncthreads();
  if (threadIdx.x == 0) {
    asm volatile("s_waitcnt vmcnt(0)" ::: "memory");
    ast(arr + bk*SLOT, phase);
    int base = (bk >> 3) * 8;
    if ((bk & 7) == 0) {
      for (;;) {
        bool ok = true;
        #pragma unroll
        for (int i = 0; i < 8; ++i) ok &= (ald(arr + (base+i)*SLOT) >= phase);
        if (ok) break;
        __builtin_amdgcn_s_sleep(1);
      }
      #pragma unroll
      for (int i = 1; i < 8; ++i) ast(rel + (base+i)*SLOT, phase);
    } else {
      while (ald(rel + bk*SLOT) < phase) __builtin_amdgcn_s_sleep(1);
    }
  }
  __syncthreads();
}

// =================== prenet: xsT[t][k=256][b=32] ===================
__global__ __launch_bounds__(256) void prenet_kernel(
    const float* __restrict__ din, const float* __restrict__ w1,
    const float* __restrict__ w2, float* __restrict__ xsT)
{
  int t = blockIdx.x;
  __shared__ float f_s[32*80];
  __shared__ float p_s[32*257];
  for (int id = threadIdx.x; id < 32*80; id += 256) {
    int b = id / 80, m = id - b*80;
    f_s[id] = (t == 0) ? 0.f : din[b*(NMEL*TMEL) + m*TMEL + (t-1)];
  }
  __syncthreads();
  for (int b = 0; b < 32; ++b) {
    int k = threadIdx.x;
    float acc = 0.f;
    #pragma unroll 4
    for (int m = 0; m < 80; ++m) acc += f_s[b*80+m] * w1[k*80+m];
    p_s[b*257+k] = fmaxf(acc, 0.f);
  }
  __syncthreads();
  int b = threadIdx.x & 31, jslot = threadIdx.x >> 5;
  for (int jj = 0; jj < 32; ++jj) {
    int j = jslot*32 + jj;
    const float* w2r = w2 + j*256;
    float acc = 0.f;
    #pragma unroll 4
    for (int kk = 0; kk < 256; ++kk) acc += p_s[b*257+kk] * w2r[kk];
    xsT[(size_t)t*8192 + j*32 + b] = fmaxf(acc, 0.f);
  }
}

// =================== pmem16[b][t][128] (fp16) ===================
__global__ __launch_bounds__(256) void pmem_kernel(
  const float* __restrict__ mem, const float* __restrict__ mw, __half* __restrict__ pm16)
{
  int b = blockIdx.y, tc = blockIdx.x;
  int a = threadIdx.x & 127, th = threadIdx.x >> 7;
  for (int i = 0; i < 8; ++i) {
    int tt = tc*16 + th + 2*i;
    const float* mrow = mem + (size_t)b*(TENC*ENCD) + (size_t)tt*ENCD;
    const float* wrow = mw + a*ENCD;
    float acc = 0.f;
    #pragma unroll 4
    for (int e4 = 0; e4 < ENCD; e4 += 4) acc += dot4(ld4(mrow+e4), ld4(wrow+e4));
    pm16[b*(TENC*ATTD) + tt*ATTD + a] = __float2half(acc);
  }
}

// =================== fp32 -> fp16 convert ===================
__global__ __launch_bounds__(256) void cvt16_kernel(
  const float* __restrict__ src, __half* __restrict__ dst, int n)
{
  int i = blockIdx.x*256 + threadIdx.x;
  int st = gridDim.x*256;
  for (; i < n; i += st) dst[i] = __float2half(src[i]);
}

// =================== args struct ===================
struct DecArgs {
  const float *xsT;
  const __half *awih16, *awhh16, *dwih16, *dwhh16, *qw16, *pm16;
  const float *abih, *abhh, *dbih, *dbhh;
  const float *cw, *ldw, *vw;
  const int*  mlen;
  const float *pw, *pb, *gw, *gb;
  float *ahT, *acT, *dhT, *dh, *dcT, *ah_row;
  float *ctxT, *ctx2, *aw, *awcb, *e;
  const float *memory;
  float *out_mel, *out_gate, *out_align;
  uint32 *arr, *rel;
};

// =================== pipelined GEMM + fused cell (fp16 W, Kc=128) ===================
__device__ __forceinline__ void gemm_cell(int u0, bool sA,
  const float* __restrict__ xtA, int cA, const float* __restrict__ xtB, int cB,
  const float* __restrict__ xtC, int cC,
  const __half* __restrict__ wih, int kih, const __half* __restrict__ whh,
  const float* __restrict__ bih, const float* __restrict__ bhh,
  float* __restrict__ cT, float* __restrict__ hT_out, float* __restrict__ h_row,
  float* smem)
{
  float4* Xs = (float4*)smem;          // 2 x 1024 float4
  float*  Ws = smem + 8192;            // 2 x (16*132)
  float*  G  = smem + 12416;           // 16*32
  const int tid = threadIdx.x;
  const int wave = tid >> 6, lane = tid & 63;
  const int klane = lane & 31, hlf = lane >> 5;
  const int tile = wave*2 + hlf;
  const int bg = tile & 3, rg = tile >> 2;
  const int b0 = bg*8, r0 = rg*8;
  float acc[8][8];
  #pragma unroll
  for (int i = 0; i < 8; ++i)
    #pragma unroll
    for (int j = 0; j < 8; ++j) acc[i][j] = 0.f;

  const int scol = tid & 7, skr = tid >> 3;
  const int swr = tid >> 4, skk = (tid & 15)*8;
  const int jrow = ((swr >> 2)*1024) + u0 + (swr & 3);
  const int nC = cA + cB + cC;

  float4 xv0, xv1, xv2, xv3; uint4 wv;
  #define LOADC(c) { \
    const float* xsrc; int ck; bool ssc; \
    if ((c) < cA)            { xsrc = xtA; ck = (c); ssc = sA; } \
    else if ((c) < cA + cB)  { xsrc = xtB; ck = (c) - cA; ssc = true; } \
    else                     { xsrc = xtC; ck = (c) - cA - cB; ssc = true; } \
    const float* xb_ = xsrc + (size_t)(ck*128)*32 + scol*4; \
    if (ssc) { \
      xv0 = ld4_c(xb_ + (size_t)(skr      )*32); \
      xv1 = ld4_c(xb_ + (size_t)(skr +  32)*32); \
      xv2 = ld4_c(xb_ + (size_t)(skr +  64)*32); \
      xv3 = ld4_c(xb_ + (size_t)(skr +  96)*32); \
    } else { \
      xv0 = *(const float4*)(xb_ + (size_t)(skr      )*32); \
      xv1 = *(const float4*)(xb_ + (size_t)(skr +  32)*32); \
      xv2 = *(const float4*)(xb_ + (size_t)(skr +  64)*32); \
      xv3 = *(const float4*)(xb_ + (size_t)(skr +  96)*32); \
    } \
    int kglob = (c)*128 + skk; \
    const __half* wr = (kglob < kih) ? (wih + (size_t)jrow*kih + kglob) \
                                     : (whh + (size_t)jrow*1024 + (kglob - kih)); \
    wv = *(const uint4*)wr; }

  LOADC(0);
  for (int c = 0; c < nC; ++c) {
    int bsel = c & 1;
    float4* Xb = Xs + bsel*1024;
    float*  Wb = Ws + bsel*2112;
    { int k;
      k = skr;      Xb[k*8 + (scol ^ (k & 7))] = xv0;
      k = skr + 32; Xb[k*8 + (scol ^ (k & 7))] = xv1;
      k = skr + 64; Xb[k*8 + (scol ^ (k & 7))] = xv2;
      k = skr + 96; Xb[k*8 + (scol ^ (k & 7))] = xv3; }
    { const __half* h = (const __half*)&wv;
      float* wd = Wb + swr*132 + skk;
      #pragma unroll
      for (int q = 0; q < 8; ++q) wd[q] = __half2float(h[q]); }
    __syncthreads();
    if (c + 1 < nC) LOADC(c + 1);        // prefetch flies during compute
    #pragma unroll
    for (int kk = 0; kk < 4; ++kk) {
      int k = klane + 32*kk;
      float4 x0 = Xb[k*8 + ((bg*2)     ^ (klane & 7))];
      float4 x1 = Xb[k*8 + ((bg*2 + 1) ^ (klane & 7))];
      float w[8];
      #pragma unroll
      for (int r = 0; r < 8; ++r) w[r] = Wb[(r0 + r)*132 + k];
      float xb[8] = {x0.x, x0.y, x0.z, x0.w, x1.x, x1.y, x1.z, x1.w};
      #pragma unroll
      for (int r = 0; r < 8; ++r)
        #pragma unroll
        for (int bb = 0; bb < 8; ++bb)
          acc[bb][r] += xb[bb] * w[r];
    }
  }
  #undef LOADC
  #pragma unroll
  for (int m = 16; m >= 1; m >>= 1)
    #pragma unroll
    for (int bb = 0; bb < 8; ++bb)
      #pragma unroll
      for (int r = 0; r < 8; ++r)
        acc[bb][r] += __shfl_xor(acc[bb][r], m);
  __syncthreads();
  if (klane == 0) {
    #pragma unroll
    for (int r = 0; r < 8; ++r) {
      float4 lo = make_float4(acc[0][r], acc[1][r], acc[2][r], acc[3][r]);
      float4 hi = make_float4(acc[4][r], acc[5][r], acc[6][r], acc[7][r]);
      *(float4*)(G + (r0 + r)*32 + b0)     = lo;
      *(float4*)(G + (r0 + r)*32 + b0 + 4) = hi;
    }
  }
  __syncthreads();
  if (tid < 128) {
    int du = tid >> 5, b = tid & 31;
    int u = u0 + du;
    float gi = G[(0*4+du)*32 + b] + bih[u]      + bhh[u];
    float gf = G[(1*4+du)*32 + b] + bih[1024+u] + bhh[1024+u];
    float gg = G[(2*4+du)*32 + b] + bih[2048+u] + bhh[2048+u];
    float go = G[(3*4+du)*32 + b] + bih[3072+u] + bhh[3072+u];
    float c  = cT[u*32 + b];                   // block-private: cached
    float cn = sigmf(gf)*c + sigmf(gi)*tanhf(gg);
    float h  = sigmf(go)*tanhf(cn);
    cT[u*32 + b] = cn;
    st_c(&hT_out[u*32 + b], h);
    if (h_row) st_c(&h_row[b*1024 + u], h);
  }
  __syncthreads();
}

// =================== projection helper (coherent dh/ctx reads) ===================
__device__ __forceinline__ void proj_task(int d, const float* dh, const float* ctx,
    const float* proj_w, const float* proj_b, const float* gate_w, const float* gate_b,
    float* out_mel, float* out_gate, int t)
{
  if (d >= 32*81) return;
  int b = d / 81, r = d - b*81;
  const float* w   = (r < 80) ? (proj_w + r*1792) : gate_w;
  const float* dhr = dh + b*DRNN;
  const float* cxr = ctx + b*ENCD;
  float acc = 0.f;
  for (int k = 0; k < 1024; k += 4) {
    float4 wv = ld4(w + k);
    float2 a0 = ld2_c(dhr + k), a1 = ld2_c(dhr + k + 2);
    acc += a0.x*wv.x + a0.y*wv.y + a1.x*wv.z + a1.y*wv.w;
  }
  for (int k = 0; k < 768; k += 4) {
    float4 wv = ld4(w + 1024 + k);
    float2 a0 = ld2_c(cxr + k), a1 = ld2_c(cxr + k + 2);
    acc += a0.x*wv.x + a0.y*wv.y + a1.x*wv.z + a1.y*wv.w;
  }
  if (r < 80) out_mel[(b*80 + r)*TMEL + t] = acc + proj_b[r];
  else        out_gate[b*TMEL + t]         = acc + gate_b[0];
}

// =================== P2: energies (+ folded pq) ===================
__device__ __forceinline__ void energies_phase(int bk, const DecArgs& p,
  const float* awc_old, float* smem)
{
  int b = bk >> 3, c8 = bk & 7, t0 = c8 * 50;
  float* ah_s  = smem;          // 1024
  float* pq_s  = smem + 1024;   // 128
  float* part  = smem + 1152;   // 256
  float* aw_s  = smem + 1408;   // 80
  float* awc_s = smem + 1488;   // 80
  float* loc_s = smem + 1568;   // 50*33
  float* epart = smem + 3218;   // 50*4
  int tid = threadIdx.x;
  {
    float2 v0 = ld2_c(p.ah_row + b*1024 + tid*4);
    float2 v1 = ld2_c(p.ah_row + b*1024 + tid*4 + 2);
    ah_s[tid*4]   = v0.x; ah_s[tid*4+1] = v0.y;
    ah_s[tid*4+2] = v1.x; ah_s[tid*4+3] = v1.y;
  }
  if (tid >= 96) {              // halo: 160 threads -> i in [0,160)
    int i = tid - 96;
    int h = (i < 80) ? i : i - 80;
    bool isC = i >= 80;
    int g = t0 - 15 + h;
    float v = (g >= 0 && g < TENC)
            ? (isC ? ld_c(awc_old + b*TENC + g) : ld_c(p.aw + b*TENC + g)) : 0.f;
    if (isC) awc_s[h] = v; else aw_s[h] = v;
  }
  __syncthreads();
  {
    int a = tid & 127, kh = tid >> 7;
    const __half* qr = p.qw16 + (size_t)a*1024 + kh*512;
    const float*  ar = ah_s + kh*512;
    float acc = 0.f;
    for (int k = 0; k < 512; k += 8) {
      uint4 hv = *(const uint4*)(qr + k);
      const __half2* h2 = (const __half2*)&hv;
      #pragma unroll
      for (int q = 0; q < 4; ++q) {
        float2 wf = __half22float2(h2[q]);
        acc += ar[k + q*2]*wf.x + ar[k + q*2 + 1]*wf.y;
      }
    }
    part[tid] = acc;
  }
  __syncthreads();
  if (tid < 128) pq_s[tid] = part[tid] + part[tid + 128];
  for (int id = tid; id < 50*32; id += 256) {
    int tl = id >> 5, f = id & 31;
    const float* w0 = p.cw + f*62;
    float acc = 0.f;
    #pragma unroll
    for (int k = 0; k < 31; ++k)
      acc += aw_s[tl+k]*w0[k] + awc_s[tl+k]*w0[31+k];
    loc_s[tl*33 + f] = acc;
  }
  __syncthreads();
  if (tid < 200) {
    int tl = tid >> 2, qa = tid & 3;
    int tt = t0 + tl;
    const __half* pm = p.pm16 + b*(TENC*ATTD) + tt*ATTD;
    float s = 0.f;
    for (int a = qa*32; a < qa*32 + 32; ++a) {
      const float* lw = p.ldw + a*32;
      float pl = 0.f;
      #pragma unroll 8
      for (int f = 0; f < 32; ++f) pl += loc_s[tl*33 + f] * lw[f];
      s += p.vw[a] * tanhf(pq_s[a] + __half2float(pm[a]) + pl);
    }
    epart[tl*4 + qa] = s;
  }
  __syncthreads();
  if (tid < 50) {
    int tt = t0 + tid;
    float v = epart[tid*4] + epart[tid*4+1] + epart[tid*4+2] + epart[tid*4+3];
    if (tt >= p.mlen[b]) v = -1000000000.0f;
    st_c(p.e + b*TENC + tt, v);
  }
  __syncthreads();
}

// =================== P3: softmax + LDS-resident ctx ===================
__device__ __forceinline__ void sm_ctx_phase(int bk, int t, const DecArgs& p,
  const float* awc_old, float* awc_new, float* ctx_cur, const __half2* mem_s,
  float* smem)
{
  int b = bk >> 3, jc = bk & 7, j0 = jc*96;
  int tid = threadIdx.x;
  float* red   = smem;         // 256
  float* aw_s  = smem + 256;   // 400
  float* cpart = smem + 656;   // 384
  float v0 = ld_c(p.e + b*TENC + tid);
  float v1 = (tid + 256 < TENC) ? ld_c(p.e + b*TENC + tid + 256) : -3.0e38f;
  red[tid] = fmaxf(v0, v1); __syncthreads();
  for (int s = 128; s > 0; s >>= 1) {
    if (tid < s) red[tid] = fmaxf(red[tid], red[tid+s]);
    __syncthreads();
  }
  float mx = red[0]; __syncthreads();
  float p0 = __expf(v0 - mx);
  float p1 = (tid + 256 < TENC) ? __expf(v1 - mx) : 0.f;
  red[tid] = p0 + p1; __syncthreads();
  for (int s = 128; s > 0; s >>= 1) {
    if (tid < s) red[tid] += red[tid+s];
    __syncthreads();
  }
  float inv = 1.f / red[0];
  aw_s[tid] = p0 * inv;
  if (tid + 256 < TENC) aw_s[tid + 256] = p1 * inv;
  __syncthreads();
  if (tid < 192) {
    int jp = tid % 48, h = tid / 48;
    float ax = 0.f, ay = 0.f;
    for (int tt = h*100; tt < h*100 + 100; ++tt) {
      float av = aw_s[tt];
      float2 m = __half22float2(mem_s[tt*48 + jp]);
      ax += av * m.x; ay += av * m.y;
    }
    cpart[(h*48 + jp)*2]     = ax;
    cpart[(h*48 + jp)*2 + 1] = ay;
  }
  __syncthreads();
  if (tid < 48) {
    float sx = cpart[tid*2]        + cpart[(48+tid)*2]
             + cpart[(96+tid)*2]   + cpart[(144+tid)*2];
    float sy = cpart[tid*2+1]      + cpart[(48+tid)*2+1]
             + cpart[(96+tid)*2+1] + cpart[(144+tid)*2+1];
    int j = j0 + tid*2;
    st_c(&p.ctxT[(size_t)j*32 + b], sx);
    st_c(&p.ctxT[(size_t)(j+1)*32 + b], sy);
    st_c(&ctx_cur[b*ENCD + j], sx);
    st_c(&ctx_cur[b*ENCD + j + 1], sy);
  }
  if (jc == 0) {
    for (int i = tid; i < TENC; i += 256) {
      float a = aw_s[i];
      st_c(&p.aw[b*TENC + i], a);
      st_c(&awc_new[b*TENC + i], ld_c(&awc_old[b*TENC + i]) + a);
      p.out_align[((size_t)b*TMEL + t)*TENC + i] = a;
    }
  }
  __syncthreads();
}

// =================== THE persistent kernel ===================
__global__ __launch_bounds__(256, 1) void decoder_loop(DecArgs p)
{
  __shared__ __align__(16) float scratch[12928];   // 51.7 KB (union)
  __shared__ __half2 mem_s[400*48];                // 76.8 KB (persistent)
  const int bk = blockIdx.x;
  const int u0 = bk * 4;
  uint32 phase = 0;

  { // preload memory slice (immutable -> cached loads)
    int b = bk >> 3, jc = bk & 7, j0 = jc*96;
    const float* mb = p.memory + (size_t)b*(TENC*ENCD);
    for (int idx = threadIdx.x; idx < 400*48; idx += 256) {
      int tt = idx / 48, jp = idx - tt*48;
      float m0 = mb[(size_t)tt*ENCD + j0 + jp*2];
      float m1 = mb[(size_t)tt*ENCD + j0 + jp*2 + 1];
      mem_s[idx] = __floats2half2_rn(m0, m1);
    }
  }
  __syncthreads();

  for (int t = 0; t < TMEL; ++t) {
    const float* ahT_rd  = p.ahT  + ((t+1)&1)*32768;
    float*       ahT_wr  = p.ahT  + (t&1)*32768;
    const float* dhT_rd  = p.dhT  + ((t+1)&1)*32768;
    float*       dhT_wr  = p.dhT  + (t&1)*32768;
    const float* awc_old = p.awcb + ((t+1)&1)*12800;
    float*       awc_new = p.awcb + (t&1)*12800;
    float*       ctx_cur = p.ctx2 + (t&1)*24576;
    const float* ctx_prev= p.ctx2 + ((t+1)&1)*24576;

    // P1: att-GEMM + cell (writes ahT, ah_row)
    gemm_cell(u0, false, p.xsT + (size_t)t*8192, 2, p.ctxT, 6, ahT_rd, 8,
              p.awih16, 1024, p.awhh16, p.abih, p.abhh,
              p.acT, ahT_wr, p.ah_row, scratch);
    bar_grid(p.arr, p.rel, ++phase, bk);

    // P2: energies (+pq)
    energies_phase(bk, p, awc_old, scratch);
    bar_group(p.arr, p.rel, ++phase, bk);     // e deps are within the b-group

    // P3: softmax + ctx (all blocks) + proj(t-1) (16 blocks)
    sm_ctx_phase(bk, t, p, awc_old, awc_new, ctx_cur, mem_s, scratch);
    if ((bk & 7) == 7 && (bk >> 3) < 16 && t > 0) {
      int d = (bk >> 3)*256 + threadIdx.x;
      proj_task(d, p.dh, ctx_prev, p.pw, p.pb, p.gw, p.gb,
                p.out_mel, p.out_gate, t-1);
    }
    bar_grid(p.arr, p.rel, ++phase, bk);

    // P4: dec-GEMM + cell (writes dhT, dh)
    gemm_cell(u0, true, ahT_wr, 8, p.ctxT, 6, dhT_rd, 8,
              p.dwih16, 1792, p.dwhh16, p.dbih, p.dbhh,
              p.dcT, dhT_wr, p.dh, scratch);
    bar_grid(p.arr, p.rel, ++phase, bk);
  }

  // final projection (t = TMEL-1)
  if ((bk & 7) == 7 && (bk >> 3) < 16) {
    int d = (bk >> 3)*256 + threadIdx.x;
    proj_task(d, p.dh, p.ctx2 + ((TMEL-1)&1)*24576, p.pw, p.pb, p.gw, p.gb,
              p.out_mel, p.out_gate, TMEL-1);
  }
}

extern "C" void kernel_launch(void* const* d_in, const int* in_sizes, int n_in,
                              void* d_out, int out_size, void* d_ws, size_t ws_size,
                              hipStream_t stream)
{
  const float* memory = (const float*)d_in[0];
  const float* din    = (const float*)d_in[1];
  const float* w1     = (const float*)d_in[3];
  const float* w2     = (const float*)d_in[4];
  const float* awih   = (const float*)d_in[5];
  const float* awhh   = (const float*)d_in[6];
  const float* abih   = (const float*)d_in[7];
  const float* abhh   = (const float*)d_in[8];
  const float* q_w    = (const float*)d_in[9];
  const float* mem_w  = (const float*)d_in[10];
  const float* v_w    = (const float*)d_in[11];
  const float* cw     = (const float*)d_in[12];
  const float* ldw    = (const float*)d_in[13];
  const float* dwih   = (const float*)d_in[14];
  const float* dwhh   = (const float*)d_in[15];
  const float* dbih   = (const float*)d_in[16];
  const float* dbhh   = (const float*)d_in[17];
  const float* pw     = (const float*)d_in[18];
  const float* pb     = (const float*)d_in[19];
  const float* gw     = (const float*)d_in[20];
  const float* gb     = (const float*)d_in[21];
  const int*   mlen   = (const int*)d_in[22];

  float* p = (float*)d_ws;
  float* xsT    = p;              p += 800*256*32;
  __half* awih16 = (__half*)p;    p += 2097152;
  __half* awhh16 = (__half*)p;    p += 2097152;
  __half* dwih16 = (__half*)p;    p += 3670016;
  __half* dwhh16 = (__half*)p;    p += 2097152;
  __half* qw16   = (__half*)p;    p += 65536;
  __half* pm16   = (__half*)p;    p += 819200;
  // ---- zeroed state block ----
  float* zs    = p;
  uint32* arr  = (uint32*)p;      p += 256*SLOT;   // padded arrive slots
  uint32* rel  = (uint32*)p;      p += 256*SLOT;   // padded release slots
  float* ahT   = p;  p += 2*1024*32;
  float* dhT   = p;  p += 2*1024*32;
  float* dh    = p;  p += 32*1024;
  float* ah_row= p;  p += 32*1024;
  float* ctxT  = p;  p += 768*32;
  float* ctx2  = p;  p += 2*32*768;
  float* acT   = p;  p += 1024*32;
  float* dcT   = p;  p += 1024*32;
  float* aw    = p;  p += 32*400;
  float* awcb  = p;  p += 2*32*400;
  size_t zcount = (size_t)(p - zs);
  // ---- end zero block ----
  float* e     = p;  p += 32*400;

  float* out_mel   = (float*)d_out;
  float* out_gate  = out_mel + 32*80*800;
  float* out_align = out_gate + 32*800;

  hipMemsetAsync(zs, 0, zcount*sizeof(float), stream);
  prenet_kernel<<<TMEL, 256, 0, stream>>>(din, w1, w2, xsT);
  pmem_kernel<<<dim3(25,32), 256, 0, stream>>>(memory, mem_w, pm16);
  cvt16_kernel<<<256, 256, 0, stream>>>(q_w, qw16, 128*1024);
  cvt16_kernel<<<2048, 256, 0, stream>>>(awih, awih16, 4096*1024);
  cvt16_kernel<<<2048, 256, 0, stream>>>(awhh, awhh16, 4096*1024);
  cvt16_kernel<<<2048, 256, 0, stream>>>(dwih, dwih16, 4096*1792);
  cvt16_kernel<<<2048, 256, 0, stream>>>(dwhh, dwhh16, 4096*1024);

  DecArgs a;
  a.xsT = xsT;
  a.awih16 = awih16; a.awhh16 = awhh16; a.dwih16 = dwih16; a.dwhh16 = dwhh16;
  a.qw16 = qw16; a.pm16 = pm16;
  a.abih = abih; a.abhh = abhh; a.dbih = dbih; a.dbhh = dbhh;
  a.cw = cw; a.ldw = ldw; a.vw = v_w; a.mlen = mlen;
  a.pw = pw; a.pb = pb; a.gw = gw; a.gb = gb;
  a.ahT = ahT; a.acT = acT; a.dhT = dhT; a.dh = dh; a.dcT = dcT; a.ah_row = ah_row;
  a.ctxT = ctxT; a.ctx2 = ctx2; a.aw = aw; a.awcb = awcb; a.e = e;
  a.memory = memory;
  a.out_mel = out_mel; a.out_gate = out_gate; a.out_align = out_align;
  a.arr = arr; a.rel = rel;

  decoder_loop<<<NBLK, 256, 0, stream>>>(a);
}

// Round 14
// 167241.357 us; speedup vs baseline: 1.3445x; 1.0902x over previous
//
#include <hip/hip_runtime.h>
#include <hip/hip_fp16.h>
#include <math.h>

#define TENC 400
#define TMEL 800
#define NMEL 80
#define ENCD 768
#define PRE  256
#define ARNN 1024
#define DRNN 1024
#define ATTD 128
#define NBLK 256
#define SLOT 32   // 128B-padded barrier slots

typedef unsigned uint32;

__device__ __forceinline__ float4 ld4(const float* p){ return *(const float4*)p; }
__device__ __forceinline__ float dot4(float4 a, float4 b){
  return a.x*b.x + a.y*b.y + a.z*b.z + a.w*b.w;
}
__device__ __forceinline__ float sigmf(float x){ return 1.f/(1.f + __expf(-x)); }

// ---- barrier-word accessors (flags only; must bypass caches) ----
__device__ __forceinline__ uint32 ald(const uint32* p){
  return __hip_atomic_load(p, __ATOMIC_RELAXED, __HIP_MEMORY_SCOPE_AGENT);
}
__device__ __forceinline__ void ast(uint32* p, uint32 v){
  __hip_atomic_store(p, v, __ATOMIC_RELAXED, __HIP_MEMORY_SCOPE_AGENT);
}

// =================== grid barrier: release fence always, acquire-inv optional ===================
// Data protocol: producers' dirty lines written back at every barrier (wbl2);
// ONE buffer_inv per step (step-boundary barrier) clears stale L1/L2 copies.
// Correct because every cross-block buffer is read-before-write-free within a
// step (ctxT/awc/ah/dh ping-pong; e/aw/ah_row touched once per step per CU).
__device__ __forceinline__ void bar_grid(uint32* arr, uint32* rel, uint32 phase,
                                         int bk, bool acq)
{
  __syncthreads();
  if (threadIdx.x < 64) {
    if (threadIdx.x == 0) {
      __builtin_amdgcn_fence(__ATOMIC_RELEASE, "agent");   // waitcnt + wbl2
      ast(arr + bk*SLOT, phase);
    }
    if (bk == 0) {
      int lane = threadIdx.x;
      for (;;) {
        uint32 m0 = ald(arr + (lane      )*SLOT);
        uint32 m1 = ald(arr + (lane +  64)*SLOT);
        uint32 m2 = ald(arr + (lane + 128)*SLOT);
        uint32 m3 = ald(arr + (lane + 192)*SLOT);
        bool ok = (m0 >= phase) & (m1 >= phase) & (m2 >= phase) & (m3 >= phase);
        if (__all(ok)) break;
        __builtin_amdgcn_s_sleep(1);
      }
      ast(rel + (threadIdx.x      )*SLOT, phase);
      ast(rel + (threadIdx.x +  64)*SLOT, phase);
      ast(rel + (threadIdx.x + 128)*SLOT, phase);
      ast(rel + (threadIdx.x + 192)*SLOT, phase);
    } else if (threadIdx.x == 0) {
      while (ald(rel + bk*SLOT) < phase) __builtin_amdgcn_s_sleep(1);
    }
    if (threadIdx.x == 0 && acq)
      __builtin_amdgcn_fence(__ATOMIC_ACQUIRE, "agent");   // buffer_inv (1x/step)
  }
  __syncthreads();
}

// =================== 8-block group barrier (release only) ===================
__device__ __forceinline__ void bar_group(uint32* arr, uint32* rel, uint32 phase, int bk)
{
  __syncthreads();
  if (threadIdx.x == 0) {
    __builtin_amdgcn_fence(__ATOMIC_RELEASE, "agent");
    ast(arr + bk*SLOT, phase);
    int base = (bk >> 3) * 8;
    if ((bk & 7) == 0) {
      for (;;) {
        bool ok = true;
        #pragma unroll
        for (int i = 0; i < 8; ++i) ok &= (ald(arr + (base+i)*SLOT) >= phase);
        if (ok) break;
        __builtin_amdgcn_s_sleep(1);
      }
      #pragma unroll
      for (int i = 1; i < 8; ++i) ast(rel + (base+i)*SLOT, phase);
    } else {
      while (ald(rel + bk*SLOT) < phase) __builtin_amdgcn_s_sleep(1);
    }
  }
  __syncthreads();
}

// =================== prenet: xsT[t][k=256][b=32] ===================
__global__ __launch_bounds__(256) void prenet_kernel(
    const float* __restrict__ din, const float* __restrict__ w1,
    const float* __restrict__ w2, float* __restrict__ xsT)
{
  int t = blockIdx.x;
  __shared__ float f_s[32*80];
  __shared__ float p_s[32*257];
  for (int id = threadIdx.x; id < 32*80; id += 256) {
    int b = id / 80, m = id - b*80;
    f_s[id] = (t == 0) ? 0.f : din[b*(NMEL*TMEL) + m*TMEL + (t-1)];
  }
  __syncthreads();
  for (int b = 0; b < 32; ++b) {
    int k = threadIdx.x;
    float acc = 0.f;
    #pragma unroll 4
    for (int m = 0; m < 80; ++m) acc += f_s[b*80+m] * w1[k*80+m];
    p_s[b*257+k] = fmaxf(acc, 0.f);
  }
  __syncthreads();
  int b = threadIdx.x & 31, jslot = threadIdx.x >> 5;
  for (int jj = 0; jj < 32; ++jj) {
    int j = jslot*32 + jj;
    const float* w2r = w2 + j*256;
    float acc = 0.f;
    #pragma unroll 4
    for (int kk = 0; kk < 256; ++kk) acc += p_s[b*257+kk] * w2r[kk];
    xsT[(size_t)t*8192 + j*32 + b] = fmaxf(acc, 0.f);
  }
}

// =================== pmem16[b][t][128] (fp16) ===================
__global__ __launch_bounds__(256) void pmem_kernel(
  const float* __restrict__ mem, const float* __restrict__ mw, __half* __restrict__ pm16)
{
  int b = blockIdx.y, tc = blockIdx.x;
  int a = threadIdx.x & 127, th = threadIdx.x >> 7;
  for (int i = 0; i < 8; ++i) {
    int tt = tc*16 + th + 2*i;
    const float* mrow = mem + (size_t)b*(TENC*ENCD) + (size_t)tt*ENCD;
    const float* wrow = mw + a*ENCD;
    float acc = 0.f;
    #pragma unroll 4
    for (int e4 = 0; e4 < ENCD; e4 += 4) acc += dot4(ld4(mrow+e4), ld4(wrow+e4));
    pm16[b*(TENC*ATTD) + tt*ATTD + a] = __float2half(acc);
  }
}

// =================== fp32 -> fp16 convert ===================
__global__ __launch_bounds__(256) void cvt16_kernel(
  const float* __restrict__ src, __half* __restrict__ dst, int n)
{
  int i = blockIdx.x*256 + threadIdx.x;
  int st = gridDim.x*256;
  for (; i < n; i += st) dst[i] = __float2half(src[i]);
}

// =================== args struct ===================
struct DecArgs {
  const float *xsT;
  const __half *awih16, *awhh16, *dwih16, *dwhh16, *qw16, *pm16;
  const float *abih, *abhh, *dbih, *dbhh;
  const float *cw, *ldw, *vw;
  const int*  mlen;
  const float *pw, *pb, *gw, *gb;
  float *ahT, *acT, *dhT, *dh, *dcT, *ah_row;
  float *ctxT2, *ctx2, *aw, *awcb, *e;
  const float *memory;
  float *out_mel, *out_gate, *out_align;
  uint32 *arr, *rel;
};

// =================== pipelined GEMM + fused cell (fp16 W, Kc=128, cached loads) ===================
__device__ __forceinline__ void gemm_cell(int u0,
  const float* __restrict__ xtA, int cA, const float* __restrict__ xtB, int cB,
  const float* __restrict__ xtC, int cC,
  const __half* __restrict__ wih, int kih, const __half* __restrict__ whh,
  const float* __restrict__ bih, const float* __restrict__ bhh,
  float* __restrict__ cT, float* __restrict__ hT_out, float* __restrict__ h_row,
  float* smem)
{
  float4* Xs = (float4*)smem;          // 2 x 1024 float4
  float*  Ws = smem + 8192;            // 2 x (16*132)
  float*  G  = smem + 12416;           // 16*32
  const int tid = threadIdx.x;
  const int wave = tid >> 6, lane = tid & 63;
  const int klane = lane & 31, hlf = lane >> 5;
  const int tile = wave*2 + hlf;
  const int bg = tile & 3, rg = tile >> 2;
  const int b0 = bg*8, r0 = rg*8;
  float acc[8][8];
  #pragma unroll
  for (int i = 0; i < 8; ++i)
    #pragma unroll
    for (int j = 0; j < 8; ++j) acc[i][j] = 0.f;

  const int scol = tid & 7, skr = tid >> 3;
  const int swr = tid >> 4, skk = (tid & 15)*8;
  const int jrow = ((swr >> 2)*1024) + u0 + (swr & 3);
  const int nC = cA + cB + cC;

  float4 xv0, xv1, xv2, xv3; uint4 wv;
  #define LOADC(c) { \
    const float* xsrc; int ck; \
    if ((c) < cA)            { xsrc = xtA; ck = (c); } \
    else if ((c) < cA + cB)  { xsrc = xtB; ck = (c) - cA; } \
    else                     { xsrc = xtC; ck = (c) - cA - cB; } \
    const float* xb_ = xsrc + (size_t)(ck*128)*32 + scol*4; \
    xv0 = ld4(xb_ + (size_t)(skr      )*32); \
    xv1 = ld4(xb_ + (size_t)(skr +  32)*32); \
    xv2 = ld4(xb_ + (size_t)(skr +  64)*32); \
    xv3 = ld4(xb_ + (size_t)(skr +  96)*32); \
    int kglob = (c)*128 + skk; \
    const __half* wr = (kglob < kih) ? (wih + (size_t)jrow*kih + kglob) \
                                     : (whh + (size_t)jrow*1024 + (kglob - kih)); \
    wv = *(const uint4*)wr; }

  LOADC(0);
  for (int c = 0; c < nC; ++c) {
    int bsel = c & 1;
    float4* Xb = Xs + bsel*1024;
    float*  Wb = Ws + bsel*2112;
    { int k;
      k = skr;      Xb[k*8 + (scol ^ (k & 7))] = xv0;
      k = skr + 32; Xb[k*8 + (scol ^ (k & 7))] = xv1;
      k = skr + 64; Xb[k*8 + (scol ^ (k & 7))] = xv2;
      k = skr + 96; Xb[k*8 + (scol ^ (k & 7))] = xv3; }
    { const __half* h = (const __half*)&wv;
      float* wd = Wb + swr*132 + skk;
      #pragma unroll
      for (int q = 0; q < 8; ++q) wd[q] = __half2float(h[q]); }
    __syncthreads();
    if (c + 1 < nC) LOADC(c + 1);        // prefetch flies during compute
    #pragma unroll
    for (int kk = 0; kk < 4; ++kk) {
      int k = klane + 32*kk;
      float4 x0 = Xb[k*8 + ((bg*2)     ^ (klane & 7))];
      float4 x1 = Xb[k*8 + ((bg*2 + 1) ^ (klane & 7))];
      float w[8];
      #pragma unroll
      for (int r = 0; r < 8; ++r) w[r] = Wb[(r0 + r)*132 + k];
      float xb[8] = {x0.x, x0.y, x0.z, x0.w, x1.x, x1.y, x1.z, x1.w};
      #pragma unroll
      for (int r = 0; r < 8; ++r)
        #pragma unroll
        for (int bb = 0; bb < 8; ++bb)
          acc[bb][r] += xb[bb] * w[r];
    }
  }
  #undef LOADC
  #pragma unroll
  for (int m = 16; m >= 1; m >>= 1)
    #pragma unroll
    for (int bb = 0; bb < 8; ++bb)
      #pragma unroll
      for (int r = 0; r < 8; ++r)
        acc[bb][r] += __shfl_xor(acc[bb][r], m);
  __syncthreads();
  if (klane == 0) {
    #pragma unroll
    for (int r = 0; r < 8; ++r) {
      float4 lo = make_float4(acc[0][r], acc[1][r], acc[2][r], acc[3][r]);
      float4 hi = make_float4(acc[4][r], acc[5][r], acc[6][r], acc[7][r]);
      *(float4*)(G + (r0 + r)*32 + b0)     = lo;
      *(float4*)(G + (r0 + r)*32 + b0 + 4) = hi;
    }
  }
  __syncthreads();
  if (tid < 128) {
    int du = tid >> 5, b = tid & 31;
    int u = u0 + du;
    float gi = G[(0*4+du)*32 + b] + bih[u]      + bhh[u];
    float gf = G[(1*4+du)*32 + b] + bih[1024+u] + bhh[1024+u];
    float gg = G[(2*4+du)*32 + b] + bih[2048+u] + bhh[2048+u];
    float go = G[(3*4+du)*32 + b] + bih[3072+u] + bhh[3072+u];
    float c  = cT[u*32 + b];
    float cn = sigmf(gf)*c + sigmf(gi)*tanhf(gg);
    float h  = sigmf(go)*tanhf(cn);
    cT[u*32 + b]     = cn;
    hT_out[u*32 + b] = h;
    if (h_row) h_row[b*1024 + u] = h;
  }
  __syncthreads();
}

// =================== projection helper ===================
__device__ __forceinline__ void proj_task(int d, const float* dh, const float* ctx,
    const float* proj_w, const float* proj_b, const float* gate_w, const float* gate_b,
    float* out_mel, float* out_gate, int t)
{
  if (d >= 32*81) return;
  int b = d / 81, r = d - b*81;
  const float* w   = (r < 80) ? (proj_w + r*1792) : gate_w;
  const float* dhr = dh + b*DRNN;
  const float* cxr = ctx + b*ENCD;
  float acc = 0.f;
  #pragma unroll 4
  for (int k = 0; k < 1024; k += 4) acc += dot4(ld4(dhr+k), ld4(w+k));
  #pragma unroll 4
  for (int k = 0; k < 768;  k += 4) acc += dot4(ld4(cxr+k), ld4(w+1024+k));
  if (r < 80) out_mel[(b*80 + r)*TMEL + t] = acc + proj_b[r];
  else        out_gate[b*TMEL + t]         = acc + gate_b[0];
}

// =================== P2: energies (+ folded pq) ===================
__device__ __forceinline__ void energies_phase(int bk, const DecArgs& p,
  const float* awc_old, float* smem)
{
  int b = bk >> 3, c8 = bk & 7, t0 = c8 * 50;
  float* ah_s  = smem;          // 1024
  float* pq_s  = smem + 1024;   // 128
  float* part  = smem + 1152;   // 256
  float* aw_s  = smem + 1408;   // 80
  float* awc_s = smem + 1488;   // 80
  float* loc_s = smem + 1568;   // 50*33
  float* epart = smem + 3218;   // 50*4
  int tid = threadIdx.x;
  {
    float4 v = ld4(p.ah_row + b*1024 + tid*4);
    ah_s[tid*4] = v.x; ah_s[tid*4+1] = v.y; ah_s[tid*4+2] = v.z; ah_s[tid*4+3] = v.w;
  }
  if (tid >= 96) {              // halo: 160 threads -> i in [0,160)
    int i = tid - 96;
    int h = (i < 80) ? i : i - 80;
    bool isC = i >= 80;
    int g = t0 - 15 + h;
    float v = (g >= 0 && g < TENC)
            ? (isC ? awc_old[b*TENC+g] : p.aw[b*TENC+g]) : 0.f;
    if (isC) awc_s[h] = v; else aw_s[h] = v;
  }
  __syncthreads();
  {
    int a = tid & 127, kh = tid >> 7;
    const __half* qr = p.qw16 + (size_t)a*1024 + kh*512;
    const float*  ar = ah_s + kh*512;
    float acc = 0.f;
    for (int k = 0; k < 512; k += 8) {
      uint4 hv = *(const uint4*)(qr + k);
      const __half2* h2 = (const __half2*)&hv;
      #pragma unroll
      for (int q = 0; q < 4; ++q) {
        float2 wf = __half22float2(h2[q]);
        acc += ar[k + q*2]*wf.x + ar[k + q*2 + 1]*wf.y;
      }
    }
    part[tid] = acc;
  }
  __syncthreads();
  if (tid < 128) pq_s[tid] = part[tid] + part[tid + 128];
  for (int id = tid; id < 50*32; id += 256) {
    int tl = id >> 5, f = id & 31;
    const float* w0 = p.cw + f*62;
    float acc = 0.f;
    #pragma unroll
    for (int k = 0; k < 31; ++k)
      acc += aw_s[tl+k]*w0[k] + awc_s[tl+k]*w0[31+k];
    loc_s[tl*33 + f] = acc;
  }
  __syncthreads();
  if (tid < 200) {
    int tl = tid >> 2, qa = tid & 3;
    int tt = t0 + tl;
    const __half* pm = p.pm16 + b*(TENC*ATTD) + tt*ATTD;
    float s = 0.f;
    for (int a = qa*32; a < qa*32 + 32; ++a) {
      const float* lw = p.ldw + a*32;
      float pl = 0.f;
      #pragma unroll 8
      for (int f = 0; f < 32; ++f) pl += loc_s[tl*33 + f] * lw[f];
      s += p.vw[a] * tanhf(pq_s[a] + __half2float(pm[a]) + pl);
    }
    epart[tl*4 + qa] = s;
  }
  __syncthreads();
  if (tid < 50) {
    int tt = t0 + tid;
    float v = epart[tid*4] + epart[tid*4+1] + epart[tid*4+2] + epart[tid*4+3];
    if (tt >= p.mlen[b]) v = -1000000000.0f;
    p.e[b*TENC + tt] = v;
  }
  __syncthreads();
}

// =================== P3: softmax + LDS-resident ctx ===================
__device__ __forceinline__ void sm_ctx_phase(int bk, int t, const DecArgs& p,
  const float* awc_old, float* awc_new, float* ctxT_cur, float* ctx_cur,
  const __half2* mem_s, float* smem)
{
  int b = bk >> 3, jc = bk & 7, j0 = jc*96;
  int tid = threadIdx.x;
  float* red   = smem;         // 256
  float* aw_s  = smem + 256;   // 400
  float* cpart = smem + 656;   // 384
  float v0 = p.e[b*TENC + tid];
  float v1 = (tid + 256 < TENC) ? p.e[b*TENC + tid + 256] : -3.0e38f;
  red[tid] = fmaxf(v0, v1); __syncthreads();
  for (int s = 128; s > 0; s >>= 1) {
    if (tid < s) red[tid] = fmaxf(red[tid], red[tid+s]);
    __syncthreads();
  }
  float mx = red[0]; __syncthreads();
  float p0 = __expf(v0 - mx);
  float p1 = (tid + 256 < TENC) ? __expf(v1 - mx) : 0.f;
  red[tid] = p0 + p1; __syncthreads();
  for (int s = 128; s > 0; s >>= 1) {
    if (tid < s) red[tid] += red[tid+s];
    __syncthreads();
  }
  float inv = 1.f / red[0];
  aw_s[tid] = p0 * inv;
  if (tid + 256 < TENC) aw_s[tid + 256] = p1 * inv;
  __syncthreads();
  if (tid < 192) {
    int jp = tid % 48, h = tid / 48;
    float ax = 0.f, ay = 0.f;
    for (int tt = h*100; tt < h*100 + 100; ++tt) {
      float av = aw_s[tt];
      float2 m = __half22float2(mem_s[tt*48 + jp]);
      ax += av * m.x; ay += av * m.y;
    }
    cpart[(h*48 + jp)*2]     = ax;
    cpart[(h*48 + jp)*2 + 1] = ay;
  }
  __syncthreads();
  if (tid < 48) {
    float sx = cpart[tid*2]        + cpart[(48+tid)*2]
             + cpart[(96+tid)*2]   + cpart[(144+tid)*2];
    float sy = cpart[tid*2+1]      + cpart[(48+tid)*2+1]
             + cpart[(96+tid)*2+1] + cpart[(144+tid)*2+1];
    int j = j0 + tid*2;
    ctxT_cur[(size_t)j*32 + b]     = sx;
    ctxT_cur[(size_t)(j+1)*32 + b] = sy;
    ctx_cur[b*ENCD + j]     = sx;
    ctx_cur[b*ENCD + j + 1] = sy;
  }
  if (jc == 0) {
    for (int i = tid; i < TENC; i += 256) {
      float a = aw_s[i];
      p.aw[b*TENC + i] = a;
      awc_new[b*TENC + i] = awc_old[b*TENC + i] + a;
      p.out_align[((size_t)b*TMEL + t)*TENC + i] = a;
    }
  }
  __syncthreads();
}

// =================== THE persistent kernel ===================
__global__ __launch_bounds__(256, 1) void decoder_loop(DecArgs p)
{
  __shared__ __align__(16) float scratch[12928];   // 51.7 KB (union)
  __shared__ __half2 mem_s[400*48];                // 76.8 KB (persistent)
  const int bk = blockIdx.x;
  const int u0 = bk * 4;
  uint32 phase = 0;

  { // preload memory slice (immutable)
    int b = bk >> 3, jc = bk & 7, j0 = jc*96;
    const float* mb = p.memory + (size_t)b*(TENC*ENCD);
    for (int idx = threadIdx.x; idx < 400*48; idx += 256) {
      int tt = idx / 48, jp = idx - tt*48;
      float m0 = mb[(size_t)tt*ENCD + j0 + jp*2];
      float m1 = mb[(size_t)tt*ENCD + j0 + jp*2 + 1];
      mem_s[idx] = __floats2half2_rn(m0, m1);
    }
  }
  __syncthreads();

  for (int t = 0; t < TMEL; ++t) {
    const float* ahT_rd   = p.ahT   + ((t+1)&1)*32768;
    float*       ahT_wr   = p.ahT   + (t&1)*32768;
    const float* dhT_rd   = p.dhT   + ((t+1)&1)*32768;
    float*       dhT_wr   = p.dhT   + (t&1)*32768;
    const float* awc_old  = p.awcb  + ((t+1)&1)*12800;
    float*       awc_new  = p.awcb  + (t&1)*12800;
    const float* ctxT_old = p.ctxT2 + ((t+1)&1)*24576;
    float*       ctxT_cur = p.ctxT2 + (t&1)*24576;
    float*       ctx_cur  = p.ctx2  + (t&1)*24576;
    const float* ctx_prev = p.ctx2  + ((t+1)&1)*24576;

    // P1: att-GEMM + cell (reads ctxT_old, ahT_rd; writes ahT_wr, ah_row)
    gemm_cell(u0, p.xsT + (size_t)t*8192, 2, ctxT_old, 6, ahT_rd, 8,
              p.awih16, 1024, p.awhh16, p.abih, p.abhh,
              p.acT, ahT_wr, p.ah_row, scratch);
    bar_grid(p.arr, p.rel, ++phase, bk, false);

    // P2: energies (+pq)  (reads ah_row, aw, awc_old)
    energies_phase(bk, p, awc_old, scratch);
    bar_group(p.arr, p.rel, ++phase, bk);     // e deps are within the b-group

    // P3: softmax + ctx (writes ctxT_cur) + proj(t-1) (16 blocks)
    sm_ctx_phase(bk, t, p, awc_old, awc_new, ctxT_cur, ctx_cur, mem_s, scratch);
    if ((bk & 7) == 7 && (bk >> 3) < 16 && t > 0) {
      int d = (bk >> 3)*256 + threadIdx.x;
      proj_task(d, p.dh, ctx_prev, p.pw, p.pb, p.gw, p.gb,
                p.out_mel, p.out_gate, t-1);
    }
    bar_grid(p.arr, p.rel, ++phase, bk, false);

    // P4: dec-GEMM + cell (reads ahT_wr, ctxT_cur, dhT_rd; writes dhT_wr, dh)
    gemm_cell(u0, ahT_wr, 8, ctxT_cur, 6, dhT_rd, 8,
              p.dwih16, 1792, p.dwhh16, p.dbih, p.dbhh,
              p.dcT, dhT_wr, p.dh, scratch);
    bar_grid(p.arr, p.rel, ++phase, bk, true);   // step boundary: single inv/step
  }

  // final projection (t = TMEL-1)
  if ((bk & 7) == 7 && (bk >> 3) < 16) {
    int d = (bk >> 3)*256 + threadIdx.x;
    proj_task(d, p.dh, p.ctx2 + ((TMEL-1)&1)*24576, p.pw, p.pb, p.gw, p.gb,
              p.out_mel, p.out_gate, TMEL-1);
  }
}

extern "C" void kernel_launch(void* const* d_in, const int* in_sizes, int n_in,
                              void* d_out, int out_size, void* d_ws, size_t ws_size,
                              hipStream_t stream)
{
  const float* memory = (const float*)d_in[0];
  const float* din    = (const float*)d_in[1];
  const float* w1     = (const float*)d_in[3];
  const float* w2     = (const float*)d_in[4];
  const float* awih   = (const float*)d_in[5];
  const float* awhh   = (const float*)d_in[6];
  const float* abih   = (const float*)d_in[7];
  const float* abhh   = (const float*)d_in[8];
  const float* q_w    = (const float*)d_in[9];
  const float* mem_w  = (const float*)d_in[10];
  const float* v_w    = (const float*)d_in[11];
  const float* cw     = (const float*)d_in[12];
  const float* ldw    = (const float*)d_in[13];
  const float* dwih   = (const float*)d_in[14];
  const float* dwhh   = (const float*)d_in[15];
  const float* dbih   = (const float*)d_in[16];
  const float* dbhh   = (const float*)d_in[17];
  const float* pw     = (const float*)d_in[18];
  const float* pb     = (const float*)d_in[19];
  const float* gw     = (const float*)d_in[20];
  const float* gb     = (const float*)d_in[21];
  const int*   mlen   = (const int*)d_in[22];

  float* p = (float*)d_ws;
  float* xsT    = p;              p += 800*256*32;
  __half* awih16 = (__half*)p;    p += 2097152;
  __half* awhh16 = (__half*)p;    p += 2097152;
  __half* dwih16 = (__half*)p;    p += 3670016;
  __half* dwhh16 = (__half*)p;    p += 2097152;
  __half* qw16   = (__half*)p;    p += 65536;
  __half* pm16   = (__half*)p;    p += 819200;
  // ---- zeroed state block ----
  float* zs    = p;
  uint32* arr  = (uint32*)p;      p += 256*SLOT;
  uint32* rel  = (uint32*)p;      p += 256*SLOT;
  float* ahT   = p;  p += 2*1024*32;
  float* dhT   = p;  p += 2*1024*32;
  float* dh    = p;  p += 32*1024;
  float* ah_row= p;  p += 32*1024;
  float* ctxT2 = p;  p += 2*768*32;
  float* ctx2  = p;  p += 2*32*768;
  float* acT   = p;  p += 1024*32;
  float* dcT   = p;  p += 1024*32;
  float* aw    = p;  p += 32*400;
  float* awcb  = p;  p += 2*32*400;
  size_t zcount = (size_t)(p - zs);
  // ---- end zero block ----
  float* e     = p;  p += 32*400;

  float* out_mel   = (float*)d_out;
  float* out_gate  = out_mel + 32*80*800;
  float* out_align = out_gate + 32*800;

  hipMemsetAsync(zs, 0, zcount*sizeof(float), stream);
  prenet_kernel<<<TMEL, 256, 0, stream>>>(din, w1, w2, xsT);
  pmem_kernel<<<dim3(25,32), 256, 0, stream>>>(memory, mem_w, pm16);
  cvt16_kernel<<<256, 256, 0, stream>>>(q_w, qw16, 128*1024);
  cvt16_kernel<<<2048, 256, 0, stream>>>(awih, awih16, 4096*1024);
  cvt16_kernel<<<2048, 256, 0, stream>>>(awhh, awhh16, 4096*1024);
  cvt16_kernel<<<2048, 256, 0, stream>>>(dwih, dwih16, 4096*1792);
  cvt16_kernel<<<2048, 256, 0, stream>>>(dwhh, dwhh16, 4096*1024);

  DecArgs a;
  a.xsT = xsT;
  a.awih16 = awih16; a.awhh16 = awhh16; a.dwih16 = dwih16; a.dwhh16 = dwhh16;
  a.qw16 = qw16; a.pm16 = pm16;
  a.abih = abih; a.abhh = abhh; a.dbih = dbih; a.dbhh = dbhh;
  a.cw = cw; a.ldw = ldw; a.vw = v_w; a.mlen = mlen;
  a.pw = pw; a.pb = pb; a.gw = gw; a.gb = gb;
  a.ahT = ahT; a.acT = acT; a.dhT = dhT; a.dh = dh; a.dcT = dcT; a.ah_row = ah_row;
  a.ctxT2 = ctxT2; a.ctx2 = ctx2; a.aw = aw; a.awcb = awcb; a.e = e;
  a.memory = memory;
  a.out_mel = out_mel; a.out_gate = out_gate; a.out_align = out_align;
  a.arr = arr; a.rel = rel;

  decoder_loop<<<NBLK, 256, 0, stream>>>(a);
}

// Round 15
// 145317.883 us; speedup vs baseline: 1.5473x; 1.1509x over previous
//
#include <hip/hip_runtime.h>
#include <hip/hip_fp16.h>
#include <math.h>

#define TENC 400
#define TMEL 800
#define NMEL 80
#define ENCD 768
#define PRE  256
#define ARNN 1024
#define DRNN 1024
#define ATTD 128
#define NBLK 256
#define SLOT 32   // 128B-padded flag slots

typedef unsigned uint32;

__device__ __forceinline__ float4 ld4(const float* p){ return *(const float4*)p; }
__device__ __forceinline__ float sigmf(float x){ return 1.f/(1.f + __expf(-x)); }

// ---- agent-scope (sc0: L1-bypass, local-L2-hit) state accessors ----
__device__ __forceinline__ float ld_c(const float* p){
  union { unsigned u; float f; } c;
  c.u = __hip_atomic_load((const unsigned*)p, __ATOMIC_RELAXED, __HIP_MEMORY_SCOPE_AGENT);
  return c.f;
}
__device__ __forceinline__ void st_c(float* p, float v){
  union { unsigned u; float f; } c; c.f = v;
  __hip_atomic_store((unsigned*)p, c.u, __ATOMIC_RELAXED, __HIP_MEMORY_SCOPE_AGENT);
}
__device__ __forceinline__ float4 ld4_c(const float* p){
  union { unsigned long long u[2]; float4 f; } c;
  c.u[0] = __hip_atomic_load((const unsigned long long*)p, __ATOMIC_RELAXED,
                             __HIP_MEMORY_SCOPE_AGENT);
  c.u[1] = __hip_atomic_load((const unsigned long long*)(p+2), __ATOMIC_RELAXED,
                             __HIP_MEMORY_SCOPE_AGENT);
  return c.f;
}
__device__ __forceinline__ void st2_c(float* p, float a, float b){
  union { unsigned long long u; float f[2]; } c; c.f[0]=a; c.f[1]=b;
  __hip_atomic_store((unsigned long long*)p, c.u, __ATOMIC_RELAXED,
                     __HIP_MEMORY_SCOPE_AGENT);
}
__device__ __forceinline__ uint32 ald(const uint32* p){
  return __hip_atomic_load(p, __ATOMIC_RELAXED, __HIP_MEMORY_SCOPE_AGENT);
}
__device__ __forceinline__ void ast(uint32* p, uint32 v){
  __hip_atomic_store(p, v, __ATOMIC_RELAXED, __HIP_MEMORY_SCOPE_AGENT);
}

// =================== XCD-local barrier (32 blocks, no fences) ===================
__device__ __forceinline__ void xbar(uint32* arr, uint32* relx, uint32 ph,
                                     int xcc, int role)
{
  __syncthreads();
  int tid = threadIdx.x;
  if (tid == 0) {
    asm volatile("s_waitcnt vmcnt(0)" ::: "memory");   // drain state stores to L2
    ast(arr + (xcc*32 + role)*SLOT, ph);
  }
  __syncthreads();
  if (role == 0) {
    if (tid < 32) {
      while (ald(arr + (xcc*32 + tid)*SLOT) < ph) __builtin_amdgcn_s_sleep(1);
    }
    __syncthreads();
    if (tid == 0) ast(relx + xcc*SLOT, ph);
  } else if (tid == 0) {
    while (ald(relx + xcc*SLOT) < ph) __builtin_amdgcn_s_sleep(1);
  }
  __syncthreads();
}

// =================== batch-group barrier (8 blocks) ===================
__device__ __forceinline__ void gbar8(uint32* arr, uint32* relg, uint32 ph,
                                      int xcc, int role)
{
  __syncthreads();
  int tid = threadIdx.x;
  int bl = role >> 3;
  if (tid == 0) {
    asm volatile("s_waitcnt vmcnt(0)" ::: "memory");
    ast(arr + (xcc*32 + role)*SLOT, ph);
  }
  __syncthreads();
  if ((role & 7) == 0) {
    if (tid < 8) {
      while (ald(arr + (xcc*32 + bl*8 + tid)*SLOT) < ph) __builtin_amdgcn_s_sleep(1);
    }
    __syncthreads();
    if (tid == 0) ast(relg + (xcc*4 + bl)*SLOT, ph);
  } else if (tid == 0) {
    while (ald(relg + (xcc*4 + bl)*SLOT) < ph) __builtin_amdgcn_s_sleep(1);
  }
  __syncthreads();
}

// =================== prenet: xsT[t][k=256][b=32] ===================
__global__ __launch_bounds__(256) void prenet_kernel(
    const float* __restrict__ din, const float* __restrict__ w1,
    const float* __restrict__ w2, float* __restrict__ xsT)
{
  int t = blockIdx.x;
  __shared__ float f_s[32*80];
  __shared__ float p_s[32*257];
  for (int id = threadIdx.x; id < 32*80; id += 256) {
    int b = id / 80, m = id - b*80;
    f_s[id] = (t == 0) ? 0.f : din[b*(NMEL*TMEL) + m*TMEL + (t-1)];
  }
  __syncthreads();
  for (int b = 0; b < 32; ++b) {
    int k = threadIdx.x;
    float acc = 0.f;
    #pragma unroll 4
    for (int m = 0; m < 80; ++m) acc += f_s[b*80+m] * w1[k*80+m];
    p_s[b*257+k] = fmaxf(acc, 0.f);
  }
  __syncthreads();
  int b = threadIdx.x & 31, jslot = threadIdx.x >> 5;
  for (int jj = 0; jj < 32; ++jj) {
    int j = jslot*32 + jj;
    const float* w2r = w2 + j*256;
    float acc = 0.f;
    #pragma unroll 4
    for (int kk = 0; kk < 256; ++kk) acc += p_s[b*257+kk] * w2r[kk];
    xsT[(size_t)t*8192 + j*32 + b] = fmaxf(acc, 0.f);
  }
}

// =================== pmem16[b][t][128] (fp16) ===================
__global__ __launch_bounds__(256) void pmem_kernel(
  const float* __restrict__ mem, const float* __restrict__ mw, __half* __restrict__ pm16)
{
  int b = blockIdx.y, tc = blockIdx.x;
  int a = threadIdx.x & 127, th = threadIdx.x >> 7;
  for (int i = 0; i < 8; ++i) {
    int tt = tc*16 + th + 2*i;
    const float* mrow = mem + (size_t)b*(TENC*ENCD) + (size_t)tt*ENCD;
    const float* wrow = mw + a*ENCD;
    float acc = 0.f;
    #pragma unroll 4
    for (int e4 = 0; e4 < ENCD; e4 += 4) {
      float4 mv = ld4(mrow+e4), wv = ld4(wrow+e4);
      acc += mv.x*wv.x + mv.y*wv.y + mv.z*wv.z + mv.w*wv.w;
    }
    pm16[b*(TENC*ATTD) + tt*ATTD + a] = __float2half(acc);
  }
}

// =================== fp32 -> fp16 convert ===================
__global__ __launch_bounds__(256) void cvt16_kernel(
  const float* __restrict__ src, __half* __restrict__ dst, int n)
{
  int i = blockIdx.x*256 + threadIdx.x;
  int st = gridDim.x*256;
  for (; i < n; i += st) dst[i] = __float2half(src[i]);
}

// =================== args ===================
struct DecArgs {
  const float *xsT;
  const __half *awih16, *awhh16, *dwih16, *dwhh16, *qw16, *pm16;
  const float *abih, *abhh, *dbih, *dbhh;
  const float *cw, *ldw, *vw;
  const int*  mlen;
  const float *pw, *pb, *gw, *gb;
  const float *memory;
  float *ahX, *dhX, *ctxX, *awX, *awcX, *eX;
  float *out_mel, *out_gate, *out_align;
  uint32 *roleCtr, *arr, *relx, *relg;
};

// =================== X staging (fp32 [k][4b] with XOR swizzle) ===================
__device__ __forceinline__ void stage_att(const float* __restrict__ xsT_t, int b0,
  const float* __restrict__ ctxX, const float* __restrict__ ahR, float* Xs)
{
  int tid = threadIdx.x;
  char* Xb = (char*)Xs;
  #pragma unroll
  for (int i = 0; i < 8; ++i) {
    int k = tid + i*256;
    float4 v;
    if (k < 256)        v = ld4(xsT_t + (size_t)k*32 + b0);
    else if (k < 1024)  v = ld4_c(ctxX + (size_t)(k-256)*4);
    else                v = ld4_c(ahR  + (size_t)(k-1024)*4);
    *(float4*)(Xb + (((size_t)k*16) ^ (size_t)(((k>>3)&7)<<4))) = v;
  }
}
__device__ __forceinline__ void stage_dec(const float* __restrict__ ahW,
  const float* __restrict__ ctxX, const float* __restrict__ dhR, float* Xs)
{
  int tid = threadIdx.x;
  char* Xb = (char*)Xs;
  #pragma unroll
  for (int i = 0; i < 11; ++i) {
    int k = tid + i*256;
    float4 v;
    if (k < 1024)       v = ld4_c(ahW  + (size_t)k*4);
    else if (k < 1792)  v = ld4_c(ctxX + (size_t)(k-1024)*4);
    else                v = ld4_c(dhR  + (size_t)(k-1792)*4);
    *(float4*)(Xb + (((size_t)k*16) ^ (size_t)(((k>>3)&7)<<4))) = v;
  }
}

// =================== GEMM: 128 rows (4 gates x 32 u) x 4 batches ===================
#define RS_ROUND(m, n) { bool hi = (lane & m) != 0; \
  _Pragma("unroll") for (int i = 0; i < n; ++i) { \
    float v = hi ? acc[i] : acc[i+n]; \
    float o = __shfl_xor(v, m); \
    acc[i] = (hi ? acc[i+n] : acc[i]) + o; } }

__device__ void gemm_xcd(const __half* __restrict__ wih, int kih,
                         const __half* __restrict__ whh, int u0g,
                         int ktFull, int ktail, const float* Xs, float* G)
{
  const int tid = threadIdx.x;
  const int g = tid >> 6, lane = tid & 63;
  float acc[128];
  #pragma unroll
  for (int i = 0; i < 128; ++i) acc[i] = 0.f;
  const size_t swz = (size_t)((lane & 7) << 4);
  const char* Xb = (const char*)Xs;

  for (int kt = 0; kt < ktFull; ++kt) {
    int k0 = kt*512 + lane*8;
    float4 xr[8];
    #pragma unroll
    for (int j = 0; j < 8; ++j)
      xr[j] = *(const float4*)(Xb + (((size_t)(k0+j)*16) ^ swz));
    bool ih = k0 < kih;
    const __half* wb = ih ? (wih + (size_t)(g*1024+u0g)*kih + k0)
                          : (whh + (size_t)(g*1024+u0g)*1024 + (k0 - kih));
    const size_t wstr = ih ? (size_t)kih : (size_t)1024;
    #pragma unroll
    for (int u = 0; u < 32; ++u) {
      uint4 wv = *(const uint4*)(wb + u*wstr);
      const __half* wh = (const __half*)&wv;
      #pragma unroll
      for (int j = 0; j < 8; ++j) {
        float wk = __half2float(wh[j]);
        float4 x = xr[j];
        acc[u*4+0] += wk*x.x; acc[u*4+1] += wk*x.y;
        acc[u*4+2] += wk*x.z; acc[u*4+3] += wk*x.w;
      }
    }
  }
  if (ktail) {
    int k0 = ktFull*512 + lane*8;
    if (lane*8 < ktail) {
      float4 xr[8];
      #pragma unroll
      for (int j = 0; j < 8; ++j)
        xr[j] = *(const float4*)(Xb + (((size_t)(k0+j)*16) ^ swz));
      bool ih = k0 < kih;
      const __half* wb = ih ? (wih + (size_t)(g*1024+u0g)*kih + k0)
                            : (whh + (size_t)(g*1024+u0g)*1024 + (k0 - kih));
      const size_t wstr = ih ? (size_t)kih : (size_t)1024;
      #pragma unroll
      for (int u = 0; u < 32; ++u) {
        uint4 wv = *(const uint4*)(wb + u*wstr);
        const __half* wh = (const __half*)&wv;
        #pragma unroll
        for (int j = 0; j < 8; ++j) {
          float wk = __half2float(wh[j]);
          float4 x = xr[j];
          acc[u*4+0] += wk*x.x; acc[u*4+1] += wk*x.y;
          acc[u*4+2] += wk*x.z; acc[u*4+3] += wk*x.w;
        }
      }
    }
  }
  RS_ROUND(32,64) RS_ROUND(16,32) RS_ROUND(8,16)
  RS_ROUND(4,8)   RS_ROUND(2,4)   RS_ROUND(1,2)
  {
    int pidx = lane*2;
    int u = pidx >> 2, b = pidx & 3;        // b in {0,2}
    *(float2*)(G + g*128 + u*4 + b) = make_float2(acc[0], acc[1]);
  }
}

// =================== LSTM cell (c in registers) ===================
__device__ __forceinline__ void cell_x(const float* G, int u0g,
  const float* __restrict__ bih, const float* __restrict__ bhh,
  float& creg, float* hbuf, float* __restrict__ hXw)
{
  int tid = threadIdx.x;
  __syncthreads();
  if (tid < 128) {
    int u = tid >> 2, b = tid & 3;
    int uu = u0g + u;
    float gi = G[0*128 + u*4+b] + bih[uu]        + bhh[uu];
    float gf = G[1*128 + u*4+b] + bih[1024+uu]   + bhh[1024+uu];
    float gg = G[2*128 + u*4+b] + bih[2048+uu]   + bhh[2048+uu];
    float go = G[3*128 + u*4+b] + bih[3072+uu]   + bhh[3072+uu];
    float cn = sigmf(gf)*creg + sigmf(gi)*tanhf(gg);
    creg = cn;
    hbuf[tid] = sigmf(go)*tanhf(cn);
  }
  __syncthreads();
  if (tid < 32) {
    float4 hv = *(float4*)(hbuf + tid*4);
    st2_c(hXw + (size_t)(u0g + tid)*4,     hv.x, hv.y);
    st2_c(hXw + (size_t)(u0g + tid)*4 + 2, hv.z, hv.w);
  }
  __syncthreads();
}

// =================== projection (XCD rows 0..323) ===================
__device__ void proj_x(int role, int xcc, int t,
  const float* __restrict__ dhR, const float* __restrict__ ctxX, const DecArgs& p)
{
  int tid = threadIdx.x;
  int w = tid >> 6, lane = tid & 63;
  int base = role*10 + (role < 4 ? role : 4);
  int cnt  = (role < 4) ? 11 : 10;
  for (int i = w; i < cnt; i += 4) {
    int d = base + i;
    int bl = d / 81, r = d - bl*81;
    const float* wr = (r < 80) ? (p.pw + (size_t)r*1792) : p.gw;
    float a = 0.f;
    #pragma unroll 4
    for (int ii = 0; ii < 28; ++ii) {
      int k = lane + ii*64;
      float x = (k < 1024) ? ld_c(dhR + (size_t)k*4 + bl)
                           : ld_c(ctxX + (size_t)(k-1024)*4 + bl);
      a += x * wr[k];
    }
    #pragma unroll
    for (int m = 32; m >= 1; m >>= 1) a += __shfl_xor(a, m);
    if (lane == 0) {
      int b = xcc*4 + bl;
      if (r < 80) p.out_mel[((size_t)b*80 + r)*TMEL + t] = a + p.pb[r];
      else        p.out_gate[(size_t)b*TMEL + t]         = a + p.gb[0];
    }
  }
}

// =================== P2: energies (+pq) for (bl, c8) ===================
__device__ void energies_x(int bl, int c8, int xcc, const DecArgs& p,
  const float* __restrict__ ahW, const float* __restrict__ awXl,
  const float* __restrict__ awcXl, float* __restrict__ eXl, float* scr)
{
  int t0 = c8*50;
  float* ah_s  = scr;           // 1024
  float* pq_s  = scr + 1024;    // 128
  float* part  = scr + 1152;    // 256
  float* aw_s  = scr + 1408;    // 80
  float* awc_s = scr + 1488;    // 80
  float* loc_s = scr + 1568;    // 50*33
  float* epart = scr + 3218;    // 200
  int tid = threadIdx.x;
  #pragma unroll
  for (int i = 0; i < 4; ++i) {
    int u = tid + i*256;
    ah_s[u] = ld_c(ahW + (size_t)u*4 + bl);
  }
  if (tid >= 96) {              // 160 threads -> halo i in [0,160)
    int i = tid - 96;
    int h = (i < 80) ? i : i - 80;
    bool isC = i >= 80;
    int gidx = t0 - 15 + h;
    float v = (gidx >= 0 && gidx < TENC)
            ? (isC ? ld_c(awcXl + gidx) : ld_c(awXl + gidx)) : 0.f;
    if (isC) awc_s[h] = v; else aw_s[h] = v;
  }
  __syncthreads();
  {
    int a = tid & 127, kh = tid >> 7;
    const __half* qr = p.qw16 + (size_t)a*1024 + kh*512;
    const float*  ar = ah_s + kh*512;
    float acc = 0.f;
    for (int k = 0; k < 512; k += 8) {
      uint4 hv = *(const uint4*)(qr + k);
      const __half2* h2 = (const __half2*)&hv;
      #pragma unroll
      for (int q = 0; q < 4; ++q) {
        float2 wf = __half22float2(h2[q]);
        acc += ar[k+q*2]*wf.x + ar[k+q*2+1]*wf.y;
      }
    }
    part[tid] = acc;
  }
  __syncthreads();
  if (tid < 128) pq_s[tid] = part[tid] + part[tid+128];
  for (int id = tid; id < 50*32; id += 256) {
    int tl = id >> 5, f = id & 31;
    const float* w0 = p.cw + f*62;
    float acc = 0.f;
    #pragma unroll
    for (int k = 0; k < 31; ++k)
      acc += aw_s[tl+k]*w0[k] + awc_s[tl+k]*w0[31+k];
    loc_s[tl*33 + f] = acc;
  }
  __syncthreads();
  if (tid < 200) {
    int tl = tid >> 2, qa = tid & 3;
    int tt = t0 + tl;
    const __half* pm = p.pm16 + (size_t)(xcc*4+bl)*(TENC*ATTD) + (size_t)tt*ATTD;
    float s = 0.f;
    for (int a = qa*32; a < qa*32 + 32; ++a) {
      const float* lw = p.ldw + a*32;
      float pl = 0.f;
      #pragma unroll 8
      for (int f = 0; f < 32; ++f) pl += loc_s[tl*33 + f] * lw[f];
      s += p.vw[a] * tanhf(pq_s[a] + __half2float(pm[a]) + pl);
    }
    epart[tl*4 + qa] = s;
  }
  __syncthreads();
  if (tid < 50) {
    int tt = t0 + tid;
    float v = epart[tid*4] + epart[tid*4+1] + epart[tid*4+2] + epart[tid*4+3];
    if (tt >= p.mlen[xcc*4+bl]) v = -1000000000.0f;
    st_c(eXl + tt, v);
  }
}

// =================== P3: softmax + ctx for (bl, jc) ===================
__device__ void smctx_x(int bl, int jc, int xcc, int t, const DecArgs& p,
  const float* __restrict__ eXl, float* __restrict__ awXl, float* __restrict__ awcXl,
  float* __restrict__ ctxX, const __half2* mem_s, float* scr)
{
  float* red   = scr;          // 256
  float* aw_s  = scr + 256;    // 400
  float* cpart = scr + 656;    // 384
  int tid = threadIdx.x;
  float v0 = ld_c(eXl + tid);
  float v1 = (tid + 256 < TENC) ? ld_c(eXl + tid + 256) : -3.0e38f;
  red[tid] = fmaxf(v0, v1); __syncthreads();
  for (int s = 128; s > 0; s >>= 1) {
    if (tid < s) red[tid] = fmaxf(red[tid], red[tid+s]);
    __syncthreads();
  }
  float mx = red[0]; __syncthreads();
  float p0 = __expf(v0 - mx);
  float p1 = (tid + 256 < TENC) ? __expf(v1 - mx) : 0.f;
  red[tid] = p0 + p1; __syncthreads();
  for (int s = 128; s > 0; s >>= 1) {
    if (tid < s) red[tid] += red[tid+s];
    __syncthreads();
  }
  float inv = 1.f / red[0];
  aw_s[tid] = p0 * inv;
  if (tid + 256 < TENC) aw_s[tid + 256] = p1 * inv;
  __syncthreads();
  if (tid < 192) {
    int jp = tid % 48, h = tid / 48;
    float ax = 0.f, ay = 0.f;
    for (int tt = h*100; tt < h*100 + 100; ++tt) {
      float av = aw_s[tt];
      float2 m = __half22float2(mem_s[tt*48 + jp]);
      ax += av * m.x; ay += av * m.y;
    }
    cpart[(h*48 + jp)*2]     = ax;
    cpart[(h*48 + jp)*2 + 1] = ay;
  }
  __syncthreads();
  if (tid < 48) {
    float sx = cpart[tid*2]        + cpart[(48+tid)*2]
             + cpart[(96+tid)*2]   + cpart[(144+tid)*2];
    float sy = cpart[tid*2+1]      + cpart[(48+tid)*2+1]
             + cpart[(96+tid)*2+1] + cpart[(144+tid)*2+1];
    int j = jc*96 + tid*2;
    st_c(ctxX + (size_t)j*4 + bl, sx);
    st_c(ctxX + (size_t)(j+1)*4 + bl, sy);
  }
  if (jc == 0) {
    for (int i = tid; i < TENC; i += 256) {
      float a = aw_s[i];
      st_c(awXl + i, a);
      st_c(awcXl + i, ld_c(awcXl + i) + a);
      p.out_align[((size_t)(xcc*4+bl)*TMEL + t)*TENC + i] = a;
    }
  }
}

// =================== THE persistent XCD-partitioned kernel ===================
__global__ __launch_bounds__(256, 1) void decoder_loop(DecArgs p)
{
  __shared__ __align__(16) float Xs[11264];     // 45 KB (X stage / phase scratch)
  __shared__ __half2 mem_s[400*48];             // 76.8 KB
  __shared__ float G[512];
  __shared__ float hbuf[128];
  __shared__ int s_xcc, s_role;
  int tid = threadIdx.x;

  if (tid == 0) {
    uint32 x;
    asm volatile("s_getreg_b32 %0, hwreg(HW_REG_XCC_ID)" : "=s"(x));
    int xc = (int)(x & 7);
    s_xcc = xc;
    s_role = (int)atomicAdd(&p.roleCtr[xc], 1u);
  }
  __syncthreads();
  const int xcc = s_xcc, role = s_role & 31;
  const int u0g = role*32;
  const int bl = role >> 3, jc = role & 7;
  const int b0 = xcc*4;

  float* ctxX  = p.ctxX + (size_t)xcc*3072;
  float* awXl  = p.awX  + (size_t)xcc*1600 + bl*400;
  float* awcXl = p.awcX + (size_t)xcc*1600 + bl*400;
  float* eXl   = p.eX   + (size_t)xcc*1600 + bl*400;

  { // preload memory slice for (batch b0+bl, cols jc*96..)
    const float* mb = p.memory + (size_t)(b0+bl)*(TENC*ENCD);
    int j0 = jc*96;
    for (int idx = tid; idx < 400*48; idx += 256) {
      int tt = idx / 48, jp = idx - tt*48;
      mem_s[idx] = __floats2half2_rn(mb[(size_t)tt*ENCD + j0 + jp*2],
                                     mb[(size_t)tt*ENCD + j0 + jp*2 + 1]);
    }
  }
  float cA = 0.f, cD = 0.f;
  uint32 ph = 0;
  __syncthreads();

  for (int t = 0; t < TMEL; ++t) {
    const float* ahR = p.ahX + (size_t)((t+1)&1)*32768 + (size_t)xcc*4096;
    float*       ahW = p.ahX + (size_t)(t&1)*32768     + (size_t)xcc*4096;
    const float* dhR = p.dhX + (size_t)((t+1)&1)*32768 + (size_t)xcc*4096;
    float*       dhW = p.dhX + (size_t)(t&1)*32768     + (size_t)xcc*4096;

    // ---- P1: att-GEMM + cell (+ proj(t-1)) ----
    stage_att(p.xsT + (size_t)t*8192, b0, ctxX, ahR, Xs);
    __syncthreads();
    if (t > 0) proj_x(role, xcc, t-1, dhR, ctxX, p);
    gemm_xcd(p.awih16, 1024, p.awhh16, u0g, 4, 0, Xs, G);
    cell_x(G, u0g, p.abih, p.abhh, cA, hbuf, ahW);
    xbar(p.arr, p.relx, ++ph, xcc, role);

    // ---- P2: energies (+pq) ----
    energies_x(bl, jc, xcc, p, ahW, awXl, awcXl, eXl, Xs);
    gbar8(p.arr, p.relg, ++ph, xcc, role);

    // ---- P3: softmax + ctx ----
    smctx_x(bl, jc, xcc, t, p, eXl, awXl, awcXl, ctxX, mem_s, Xs);
    xbar(p.arr, p.relx, ++ph, xcc, role);

    // ---- P4: dec-GEMM + cell ----
    stage_dec(ahW, ctxX, dhR, Xs);
    __syncthreads();
    gemm_xcd(p.dwih16, 1792, p.dwhh16, u0g, 5, 256, Xs, G);
    cell_x(G, u0g, p.dbih, p.dbhh, cD, hbuf, dhW);
    xbar(p.arr, p.relx, ++ph, xcc, role);
  }

  // final projection (t = TMEL-1)
  proj_x(role, xcc, TMEL-1,
         p.dhX + (size_t)((TMEL-1)&1)*32768 + (size_t)xcc*4096, ctxX, p);
}

extern "C" void kernel_launch(void* const* d_in, const int* in_sizes, int n_in,
                              void* d_out, int out_size, void* d_ws, size_t ws_size,
                              hipStream_t stream)
{
  const float* memory = (const float*)d_in[0];
  const float* din    = (const float*)d_in[1];
  const float* w1     = (const float*)d_in[3];
  const float* w2     = (const float*)d_in[4];
  const float* awih   = (const float*)d_in[5];
  const float* awhh   = (const float*)d_in[6];
  const float* abih   = (const float*)d_in[7];
  const float* abhh   = (const float*)d_in[8];
  const float* q_w    = (const float*)d_in[9];
  const float* mem_w  = (const float*)d_in[10];
  const float* v_w    = (const float*)d_in[11];
  const float* cw     = (const float*)d_in[12];
  const float* ldw    = (const float*)d_in[13];
  const float* dwih   = (const float*)d_in[14];
  const float* dwhh   = (const float*)d_in[15];
  const float* dbih   = (const float*)d_in[16];
  const float* dbhh   = (const float*)d_in[17];
  const float* pw     = (const float*)d_in[18];
  const float* pb     = (const float*)d_in[19];
  const float* gw     = (const float*)d_in[20];
  const float* gb     = (const float*)d_in[21];
  const int*   mlen   = (const int*)d_in[22];

  float* p = (float*)d_ws;
  float* xsT    = p;              p += 800*256*32;
  __half* awih16 = (__half*)p;    p += 2097152;
  __half* awhh16 = (__half*)p;    p += 2097152;
  __half* dwih16 = (__half*)p;    p += 3670016;
  __half* dwhh16 = (__half*)p;    p += 2097152;
  __half* qw16   = (__half*)p;    p += 65536;
  __half* pm16   = (__half*)p;    p += 819200;
  // ---- zeroed block ----
  float* zs      = p;
  uint32* roleCtr = (uint32*)p;   p += 8;
  uint32* arr    = (uint32*)p;    p += 256*SLOT;
  uint32* relx   = (uint32*)p;    p += 8*SLOT;
  uint32* relg   = (uint32*)p;    p += 32*SLOT;
  float* ahX     = p;             p += 2*8*1024*4;
  float* dhX     = p;             p += 2*8*1024*4;
  float* ctxX    = p;             p += 8*768*4;
  float* awX     = p;             p += 8*4*400;
  float* awcX    = p;             p += 8*4*400;
  float* eX      = p;             p += 8*4*400;
  size_t zcount  = (size_t)(p - zs);
  // ---- end zeroed block ----

  float* out_mel   = (float*)d_out;
  float* out_gate  = out_mel + 32*80*800;
  float* out_align = out_gate + 32*800;

  hipMemsetAsync(zs, 0, zcount*sizeof(float), stream);
  prenet_kernel<<<TMEL, 256, 0, stream>>>(din, w1, w2, xsT);
  pmem_kernel<<<dim3(25,32), 256, 0, stream>>>(memory, mem_w, pm16);
  cvt16_kernel<<<256, 256, 0, stream>>>(q_w, qw16, 128*1024);
  cvt16_kernel<<<2048, 256, 0, stream>>>(awih, awih16, 4096*1024);
  cvt16_kernel<<<2048, 256, 0, stream>>>(awhh, awhh16, 4096*1024);
  cvt16_kernel<<<2048, 256, 0, stream>>>(dwih, dwih16, 4096*1792);
  cvt16_kernel<<<2048, 256, 0, stream>>>(dwhh, dwhh16, 4096*1024);

  DecArgs a;
  a.xsT = xsT;
  a.awih16 = awih16; a.awhh16 = awhh16; a.dwih16 = dwih16; a.dwhh16 = dwhh16;
  a.qw16 = qw16; a.pm16 = pm16;
  a.abih = abih; a.abhh = abhh; a.dbih = dbih; a.dbhh = dbhh;
  a.cw = cw; a.ldw = ldw; a.vw = v_w; a.mlen = mlen;
  a.pw = pw; a.pb = pb; a.gw = gw; a.gb = gb;
  a.memory = memory;
  a.ahX = ahX; a.dhX = dhX; a.ctxX = ctxX; a.awX = awX; a.awcX = awcX; a.eX = eX;
  a.out_mel = out_mel; a.out_gate = out_gate; a.out_align = out_align;
  a.roleCtr = roleCtr; a.arr = arr; a.relx = relx; a.relg = relg;

  decoder_loop<<<NBLK, 256, 0, stream>>>(a);
}

// Round 16
// 113770.349 us; speedup vs baseline: 1.9764x; 1.2773x over previous
//
#include <hip/hip_runtime.h>
#include <hip/hip_fp16.h>
#include <math.h>

#define TENC 400
#define TMEL 800
#define NMEL 80
#define ENCD 768
#define PRE  256
#define ARNN 1024
#define DRNN 1024
#define ATTD 128
#define NBLK 256
#define SLOT 32   // 128B-padded flag slots

typedef unsigned uint32;

__device__ __forceinline__ float4 ld4(const float* p){ return *(const float4*)p; }
__device__ __forceinline__ float sigmf(float x){ return 1.f/(1.f + __expf(-x)); }

// ---- agent-scope (L1-bypass, local-L2-hit) state accessors ----
__device__ __forceinline__ float ld_c(const float* p){
  union { unsigned u; float f; } c;
  c.u = __hip_atomic_load((const unsigned*)p, __ATOMIC_RELAXED, __HIP_MEMORY_SCOPE_AGENT);
  return c.f;
}
__device__ __forceinline__ void st_c(float* p, float v){
  union { unsigned u; float f; } c; c.f = v;
  __hip_atomic_store((unsigned*)p, c.u, __ATOMIC_RELAXED, __HIP_MEMORY_SCOPE_AGENT);
}
__device__ __forceinline__ float4 ld4_c(const float* p){
  union { unsigned long long u[2]; float4 f; } c;
  c.u[0] = __hip_atomic_load((const unsigned long long*)p, __ATOMIC_RELAXED,
                             __HIP_MEMORY_SCOPE_AGENT);
  c.u[1] = __hip_atomic_load((const unsigned long long*)(p+2), __ATOMIC_RELAXED,
                             __HIP_MEMORY_SCOPE_AGENT);
  return c.f;
}
__device__ __forceinline__ void st2_c(float* p, float a, float b){
  union { unsigned long long u; float f[2]; } c; c.f[0]=a; c.f[1]=b;
  __hip_atomic_store((unsigned long long*)p, c.u, __ATOMIC_RELAXED,
                     __HIP_MEMORY_SCOPE_AGENT);
}
__device__ __forceinline__ uint32 ald(const uint32* p){
  return __hip_atomic_load(p, __ATOMIC_RELAXED, __HIP_MEMORY_SCOPE_AGENT);
}
__device__ __forceinline__ void ast(uint32* p, uint32 v){
  __hip_atomic_store(p, v, __ATOMIC_RELAXED, __HIP_MEMORY_SCOPE_AGENT);
}

// =================== XCD-local barrier (32 blocks, no fences) ===================
__device__ __forceinline__ void xbar(uint32* arr, uint32* relx, uint32 ph,
                                     int xcc, int role)
{
  __syncthreads();
  int tid = threadIdx.x;
  if (tid == 0) {
    asm volatile("s_waitcnt vmcnt(0)" ::: "memory");
    ast(arr + (xcc*32 + role)*SLOT, ph);
  }
  __syncthreads();
  if (role == 0) {
    if (tid < 32) {
      while (ald(arr + (xcc*32 + tid)*SLOT) < ph) __builtin_amdgcn_s_sleep(1);
    }
    __syncthreads();
    if (tid == 0) ast(relx + xcc*SLOT, ph);
  } else if (tid == 0) {
    while (ald(relx + xcc*SLOT) < ph) __builtin_amdgcn_s_sleep(1);
  }
  __syncthreads();
}

// =================== batch-group barrier (8 blocks) ===================
__device__ __forceinline__ void gbar8(uint32* arr, uint32* relg, uint32 ph,
                                      int xcc, int role)
{
  __syncthreads();
  int tid = threadIdx.x;
  int bl = role >> 3;
  if (tid == 0) {
    asm volatile("s_waitcnt vmcnt(0)" ::: "memory");
    ast(arr + (xcc*32 + role)*SLOT, ph);
  }
  __syncthreads();
  if ((role & 7) == 0) {
    if (tid < 8) {
      while (ald(arr + (xcc*32 + bl*8 + tid)*SLOT) < ph) __builtin_amdgcn_s_sleep(1);
    }
    __syncthreads();
    if (tid == 0) ast(relg + (xcc*4 + bl)*SLOT, ph);
  } else if (tid == 0) {
    while (ald(relg + (xcc*4 + bl)*SLOT) < ph) __builtin_amdgcn_s_sleep(1);
  }
  __syncthreads();
}

// =================== prenet: xsT[t][k=256][b=32] ===================
__global__ __launch_bounds__(256) void prenet_kernel(
    const float* __restrict__ din, const float* __restrict__ w1,
    const float* __restrict__ w2, float* __restrict__ xsT)
{
  int t = blockIdx.x;
  __shared__ float f_s[32*80];
  __shared__ float p_s[32*257];
  for (int id = threadIdx.x; id < 32*80; id += 256) {
    int b = id / 80, m = id - b*80;
    f_s[id] = (t == 0) ? 0.f : din[b*(NMEL*TMEL) + m*TMEL + (t-1)];
  }
  __syncthreads();
  for (int b = 0; b < 32; ++b) {
    int k = threadIdx.x;
    float acc = 0.f;
    #pragma unroll 4
    for (int m = 0; m < 80; ++m) acc += f_s[b*80+m] * w1[k*80+m];
    p_s[b*257+k] = fmaxf(acc, 0.f);
  }
  __syncthreads();
  int b = threadIdx.x & 31, jslot = threadIdx.x >> 5;
  for (int jj = 0; jj < 32; ++jj) {
    int j = jslot*32 + jj;
    const float* w2r = w2 + j*256;
    float acc = 0.f;
    #pragma unroll 4
    for (int kk = 0; kk < 256; ++kk) acc += p_s[b*257+kk] * w2r[kk];
    xsT[(size_t)t*8192 + j*32 + b] = fmaxf(acc, 0.f);
  }
}

// =================== pmem16[b][t][128] (fp16) ===================
__global__ __launch_bounds__(256) void pmem_kernel(
  const float* __restrict__ mem, const float* __restrict__ mw, __half* __restrict__ pm16)
{
  int b = blockIdx.y, tc = blockIdx.x;
  int a = threadIdx.x & 127, th = threadIdx.x >> 7;
  for (int i = 0; i < 8; ++i) {
    int tt = tc*16 + th + 2*i;
    const float* mrow = mem + (size_t)b*(TENC*ENCD) + (size_t)tt*ENCD;
    const float* wrow = mw + a*ENCD;
    float acc = 0.f;
    #pragma unroll 4
    for (int e4 = 0; e4 < ENCD; e4 += 4) {
      float4 mv = ld4(mrow+e4), wv = ld4(wrow+e4);
      acc += mv.x*wv.x + mv.y*wv.y + mv.z*wv.z + mv.w*wv.w;
    }
    pm16[b*(TENC*ATTD) + tt*ATTD + a] = __float2half(acc);
  }
}

// =================== fp32 -> fp16 convert ===================
__global__ __launch_bounds__(256) void cvt16_kernel(
  const float* __restrict__ src, __half* __restrict__ dst, int n)
{
  int i = blockIdx.x*256 + threadIdx.x;
  int st = gridDim.x*256;
  for (; i < n; i += st) dst[i] = __float2half(src[i]);
}

// =================== args ===================
struct DecArgs {
  const float *xsT;
  const __half *awih16, *awhh16, *dwih16, *dwhh16, *qw16, *pm16;
  const float *abih, *abhh, *dbih, *dbhh;
  const float *cw, *ldw, *vw;
  const int*  mlen;
  const float *pw, *pb, *gw, *gb;
  const float *memory;
  float *ahX, *dhX, *ctxX, *awX, *awcX, *eX;
  float *out_mel, *out_gate, *out_align;
  uint32 *roleCtr, *arr, *relx, *relg;
};

// =================== DMA-pipelined GEMM ===================
// Per wave g: its gate's 32 rows streamed in K-chunks of 128 halfs (8 KB)
// via global_load_lds into a 2-slot ring; X per chunk in registers.
// LDS chunk layout lands linearly as [u(32)][128 halfs].

template<int KIH>
__device__ __forceinline__ void dmaW(const __half* __restrict__ wih,
                                     const __half* __restrict__ whh,
                                     int g, int u0g, int c, char* slot, int lane)
{
  const int kk = c*128;
  const __half* base = (kk < KIH) ? wih : whh;
  const int kbase = (kk < KIH) ? kk : (kk - KIH);
  const size_t kstr = (kk < KIH) ? (size_t)KIH : (size_t)1024;
  const int r = lane >> 4, kp = lane & 15;
  const __half* src = base + (size_t)(g*1024 + u0g + r)*kstr + kbase + kp*8;
  #pragma unroll
  for (int i = 0; i < 8; ++i) {
    __builtin_amdgcn_global_load_lds(
      (const __attribute__((address_space(1))) void*)(src + (size_t)(i*4)*kstr),
      (__attribute__((address_space(3))) void*)(slot + i*1024), 16, 0, 0);
  }
}

template<int E0, int E1, bool S0W>
__device__ __forceinline__ void loadX(int c, int lane, int b0,
  const float* __restrict__ s0, const float* __restrict__ s1,
  const float* __restrict__ s2, float4& xlo, float4& xhi)
{
  int k0 = c*128 + lane*2;
  if (S0W && c < E0) {
    xlo = ld4_c(s0 + (size_t)k0*32 + b0);
    xhi = ld4_c(s0 + (size_t)(k0+1)*32 + b0);
  } else if (c < E0) {
    xlo = ld4_c(s0 + (size_t)k0*4);
    xhi = ld4_c(s0 + (size_t)k0*4 + 4);
  } else if (c < E1) {
    int kb = k0 - E0*128;
    xlo = ld4_c(s1 + (size_t)kb*4);
    xhi = ld4_c(s1 + (size_t)kb*4 + 4);
  } else {
    int kb = k0 - E1*128;
    xlo = ld4_c(s2 + (size_t)kb*4);
    xhi = ld4_c(s2 + (size_t)kb*4 + 4);
  }
}

__device__ __forceinline__ void compW(const char* slot, int lane,
                                      float4 xlo, float4 xhi, float* acc)
{
  #pragma unroll
  for (int u = 0; u < 32; ++u) {
    __half2 w2 = *(const __half2*)(slot + u*256 + lane*4);
    float2 wf = __half22float2(w2);
    acc[u*4+0] += wf.x*xlo.x + wf.y*xhi.x;
    acc[u*4+1] += wf.x*xlo.y + wf.y*xhi.y;
    acc[u*4+2] += wf.x*xlo.z + wf.y*xhi.z;
    acc[u*4+3] += wf.x*xlo.w + wf.y*xhi.w;
  }
}

#define RS_ROUND(m, n) { bool hi = (lane & m) != 0; \
  _Pragma("unroll") for (int i = 0; i < n; ++i) { \
    float v = hi ? acc[i] : acc[i+n]; \
    float o = __shfl_xor(v, m); \
    acc[i] = (hi ? acc[i+n] : acc[i]) + o; } }

#define SBAR() __builtin_amdgcn_sched_barrier(0)
#define WAITV12() { asm volatile("s_waitcnt vmcnt(12)" ::: "memory"); SBAR(); }
#define WAITV0()  { asm volatile("s_waitcnt vmcnt(0)"  ::: "memory"); SBAR(); }
#define WAITL0()  { asm volatile("s_waitcnt lgkmcnt(0)" ::: "memory"); SBAR(); }

template<int NC, int E0, int E1, int KIH, bool S0W>
__device__ void gemm_stream(const __half* __restrict__ wih,
                            const __half* __restrict__ whh,
                            int u0g, int b0,
                            const float* __restrict__ s0,
                            const float* __restrict__ s1,
                            const float* __restrict__ s2,
                            char* ringAll, float* G)
{
  const int tid = threadIdx.x;
  const int g = tid >> 6, lane = tid & 63;
  char* slot0 = ringAll + g*16384;
  char* slot1 = slot0 + 8192;
  float acc[128];
  #pragma unroll
  for (int i = 0; i < 128; ++i) acc[i] = 0.f;

  float4 xa0, xa1, xb0, xb1;
  dmaW<KIH>(wih, whh, g, u0g, 0, slot0, lane); SBAR();
  loadX<E0,E1,S0W>(0, lane, b0, s0, s1, s2, xa0, xa1); SBAR();
  dmaW<KIH>(wih, whh, g, u0g, 1, slot1, lane); SBAR();
  loadX<E0,E1,S0W>(1, lane, b0, s0, s1, s2, xb0, xb1); SBAR();

  #pragma unroll 1
  for (int c = 0; c + 2 < NC; c += 2) {
    WAITV12();
    compW(slot0, lane, xa0, xa1, acc);
    WAITL0();
    dmaW<KIH>(wih, whh, g, u0g, c+2, slot0, lane); SBAR();
    loadX<E0,E1,S0W>(c+2, lane, b0, s0, s1, s2, xa0, xa1); SBAR();
    WAITV12();
    compW(slot1, lane, xb0, xb1, acc);
    WAITL0();
    dmaW<KIH>(wih, whh, g, u0g, c+3, slot1, lane); SBAR();
    loadX<E0,E1,S0W>(c+3, lane, b0, s0, s1, s2, xb0, xb1); SBAR();
  }
  WAITV12();
  compW(slot0, lane, xa0, xa1, acc);
  WAITV0();
  compW(slot1, lane, xb0, xb1, acc);

  RS_ROUND(32,64) RS_ROUND(16,32) RS_ROUND(8,16)
  RS_ROUND(4,8)   RS_ROUND(2,4)   RS_ROUND(1,2)
  {
    int pidx = lane*2;
    int u = pidx >> 2, b = pidx & 3;
    *(float2*)(G + g*128 + u*4 + b) = make_float2(acc[0], acc[1]);
  }
}

// =================== LSTM cell (c in registers) ===================
__device__ __forceinline__ void cell_x(const float* G, int u0g,
  const float* __restrict__ bih, const float* __restrict__ bhh,
  float& creg, float* hbuf, float* __restrict__ hXw)
{
  int tid = threadIdx.x;
  __syncthreads();
  if (tid < 128) {
    int u = tid >> 2, b = tid & 3;
    int uu = u0g + u;
    float gi = G[0*128 + u*4+b] + bih[uu]        + bhh[uu];
    float gf = G[1*128 + u*4+b] + bih[1024+uu]   + bhh[1024+uu];
    float gg = G[2*128 + u*4+b] + bih[2048+uu]   + bhh[2048+uu];
    float go = G[3*128 + u*4+b] + bih[3072+uu]   + bhh[3072+uu];
    float cn = sigmf(gf)*creg + sigmf(gi)*tanhf(gg);
    creg = cn;
    hbuf[tid] = sigmf(go)*tanhf(cn);
  }
  __syncthreads();
  if (tid < 32) {
    float4 hv = *(float4*)(hbuf + tid*4);
    st2_c(hXw + (size_t)(u0g + tid)*4,     hv.x, hv.y);
    st2_c(hXw + (size_t)(u0g + tid)*4 + 2, hv.z, hv.w);
  }
  __syncthreads();
}

// =================== projection (XCD rows 0..323) ===================
__device__ void proj_x(int role, int xcc, int t,
  const float* __restrict__ dhR, const float* __restrict__ ctxX, const DecArgs& p)
{
  int tid = threadIdx.x;
  int w = tid >> 6, lane = tid & 63;
  int base = role*10 + (role < 4 ? role : 4);
  int cnt  = (role < 4) ? 11 : 10;
  for (int i = w; i < cnt; i += 4) {
    int d = base + i;
    int bl = d / 81, r = d - bl*81;
    const float* wr = (r < 80) ? (p.pw + (size_t)r*1792) : p.gw;
    float a = 0.f;
    #pragma unroll 4
    for (int ii = 0; ii < 28; ++ii) {
      int k = lane + ii*64;
      float x = (k < 1024) ? ld_c(dhR + (size_t)k*4 + bl)
                           : ld_c(ctxX + (size_t)(k-1024)*4 + bl);
      a += x * wr[k];
    }
    #pragma unroll
    for (int m = 32; m >= 1; m >>= 1) a += __shfl_xor(a, m);
    if (lane == 0) {
      int b = xcc*4 + bl;
      if (r < 80) p.out_mel[((size_t)b*80 + r)*TMEL + t] = a + p.pb[r];
      else        p.out_gate[(size_t)b*TMEL + t]         = a + p.gb[0];
    }
  }
}

// =================== P2: energies (+pq) for (bl, c8) ===================
__device__ void energies_x(int bl, int c8, int xcc, const DecArgs& p,
  const float* __restrict__ ahW, const float* __restrict__ awXl,
  const float* __restrict__ awcXl, float* __restrict__ eXl, float* scr)
{
  int t0 = c8*50;
  float* ah_s  = scr;           // 1024
  float* pq_s  = scr + 1024;    // 128
  float* part  = scr + 1152;    // 256
  float* aw_s  = scr + 1408;    // 80
  float* awc_s = scr + 1488;    // 80
  float* loc_s = scr + 1568;    // 50*33
  float* epart = scr + 3218;    // 200
  int tid = threadIdx.x;
  #pragma unroll
  for (int i = 0; i < 4; ++i) {
    int u = tid + i*256;
    ah_s[u] = ld_c(ahW + (size_t)u*4 + bl);
  }
  if (tid >= 96) {              // 160 threads -> halo i in [0,160)
    int i = tid - 96;
    int h = (i < 80) ? i : i - 80;
    bool isC = i >= 80;
    int gidx = t0 - 15 + h;
    float v = (gidx >= 0 && gidx < TENC)
            ? (isC ? ld_c(awcXl + gidx) : ld_c(awXl + gidx)) : 0.f;
    if (isC) awc_s[h] = v; else aw_s[h] = v;
  }
  __syncthreads();
  {
    int a = tid & 127, kh = tid >> 7;
    const __half* qr = p.qw16 + (size_t)a*1024 + kh*512;
    const float*  ar = ah_s + kh*512;
    float acc = 0.f;
    for (int k = 0; k < 512; k += 8) {
      uint4 hv = *(const uint4*)(qr + k);
      const __half2* h2 = (const __half2*)&hv;
      #pragma unroll
      for (int q = 0; q < 4; ++q) {
        float2 wf = __half22float2(h2[q]);
        acc += ar[k+q*2]*wf.x + ar[k+q*2+1]*wf.y;
      }
    }
    part[tid] = acc;
  }
  __syncthreads();
  if (tid < 128) pq_s[tid] = part[tid] + part[tid+128];
  for (int id = tid; id < 50*32; id += 256) {
    int tl = id >> 5, f = id & 31;
    const float* w0 = p.cw + f*62;
    float acc = 0.f;
    #pragma unroll
    for (int k = 0; k < 31; ++k)
      acc += aw_s[tl+k]*w0[k] + awc_s[tl+k]*w0[31+k];
    loc_s[tl*33 + f] = acc;
  }
  __syncthreads();
  if (tid < 200) {
    int tl = tid >> 2, qa = tid & 3;
    int tt = t0 + tl;
    const __half* pm = p.pm16 + (size_t)(xcc*4+bl)*(TENC*ATTD) + (size_t)tt*ATTD;
    float s = 0.f;
    for (int a = qa*32; a < qa*32 + 32; ++a) {
      const float* lw = p.ldw + a*32;
      float pl = 0.f;
      #pragma unroll 8
      for (int f = 0; f < 32; ++f) pl += loc_s[tl*33 + f] * lw[f];
      s += p.vw[a] * tanhf(pq_s[a] + __half2float(pm[a]) + pl);
    }
    epart[tl*4 + qa] = s;
  }
  __syncthreads();
  if (tid < 50) {
    int tt = t0 + tid;
    float v = epart[tid*4] + epart[tid*4+1] + epart[tid*4+2] + epart[tid*4+3];
    if (tt >= p.mlen[xcc*4+bl]) v = -1000000000.0f;
    st_c(eXl + tt, v);
  }
}

// =================== P3: softmax + ctx for (bl, jc) ===================
__device__ void smctx_x(int bl, int jc, int xcc, int t, const DecArgs& p,
  const float* __restrict__ eXl, float* __restrict__ awXl, float* __restrict__ awcXl,
  float* __restrict__ ctxX, const __half2* mem_s, float* scr)
{
  float* red   = scr;          // 256
  float* aw_s  = scr + 256;    // 400
  float* cpart = scr + 656;    // 384
  int tid = threadIdx.x;
  float v0 = ld_c(eXl + tid);
  float v1 = (tid + 256 < TENC) ? ld_c(eXl + tid + 256) : -3.0e38f;
  red[tid] = fmaxf(v0, v1); __syncthreads();
  for (int s = 128; s > 0; s >>= 1) {
    if (tid < s) red[tid] = fmaxf(red[tid], red[tid+s]);
    __syncthreads();
  }
  float mx = red[0]; __syncthreads();
  float p0 = __expf(v0 - mx);
  float p1 = (tid + 256 < TENC) ? __expf(v1 - mx) : 0.f;
  red[tid] = p0 + p1; __syncthreads();
  for (int s = 128; s > 0; s >>= 1) {
    if (tid < s) red[tid] += red[tid+s];
    __syncthreads();
  }
  float inv = 1.f / red[0];
  aw_s[tid] = p0 * inv;
  if (tid + 256 < TENC) aw_s[tid + 256] = p1 * inv;
  __syncthreads();
  if (tid < 192) {
    int jp = tid % 48, h = tid / 48;
    float ax = 0.f, ay = 0.f;
    for (int tt = h*100; tt < h*100 + 100; ++tt) {
      float av = aw_s[tt];
      float2 m = __half22float2(mem_s[tt*48 + jp]);
      ax += av * m.x; ay += av * m.y;
    }
    cpart[(h*48 + jp)*2]     = ax;
    cpart[(h*48 + jp)*2 + 1] = ay;
  }
  __syncthreads();
  if (tid < 48) {
    float sx = cpart[tid*2]        + cpart[(48+tid)*2]
             + cpart[(96+tid)*2]   + cpart[(144+tid)*2];
    float sy = cpart[tid*2+1]      + cpart[(48+tid)*2+1]
             + cpart[(96+tid)*2+1] + cpart[(144+tid)*2+1];
    int j = jc*96 + tid*2;
    st_c(ctxX + (size_t)j*4 + bl, sx);
    st_c(ctxX + (size_t)(j+1)*4 + bl, sy);
  }
  if (jc == 0) {
    for (int i = tid; i < TENC; i += 256) {
      float a = aw_s[i];
      st_c(awXl + i, a);
      st_c(awcXl + i, ld_c(awcXl + i) + a);
      p.out_align[((size_t)(xcc*4+bl)*TMEL + t)*TENC + i] = a;
    }
  }
}

// =================== THE persistent XCD-partitioned kernel ===================
__global__ __launch_bounds__(256, 1) void decoder_loop(DecArgs p)
{
  __shared__ __align__(16) char Wring[65536];   // 4 waves x 2 slots x 8 KB
  __shared__ __half2 mem_s[400*48];             // 76.8 KB
  __shared__ float G[512];
  __shared__ float hbuf[128];
  __shared__ int s_xcc, s_role;
  int tid = threadIdx.x;
  float* scr = (float*)Wring;                    // phase scratch (union w/ ring)

  if (tid == 0) {
    uint32 x;
    asm volatile("s_getreg_b32 %0, hwreg(HW_REG_XCC_ID)" : "=s"(x));
    int xc = (int)(x & 7);
    s_xcc = xc;
    s_role = (int)atomicAdd(&p.roleCtr[xc], 1u);
  }
  __syncthreads();
  const int xcc = s_xcc, role = s_role & 31;
  const int u0g = role*32;
  const int bl = role >> 3, jc = role & 7;
  const int b0 = xcc*4;

  float* ctxX  = p.ctxX + (size_t)xcc*3072;
  float* awXl  = p.awX  + (size_t)xcc*1600 + bl*400;
  float* awcXl = p.awcX + (size_t)xcc*1600 + bl*400;
  float* eXl   = p.eX   + (size_t)xcc*1600 + bl*400;

  { // preload memory slice for (batch b0+bl, cols jc*96..)
    const float* mb = p.memory + (size_t)(b0+bl)*(TENC*ENCD);
    int j0 = jc*96;
    for (int idx = tid; idx < 400*48; idx += 256) {
      int tt = idx / 48, jp = idx - tt*48;
      mem_s[idx] = __floats2half2_rn(mb[(size_t)tt*ENCD + j0 + jp*2],
                                     mb[(size_t)tt*ENCD + j0 + jp*2 + 1]);
    }
  }
  float cA = 0.f, cD = 0.f;
  uint32 ph = 0;
  __syncthreads();

  for (int t = 0; t < TMEL; ++t) {
    const float* ahR = p.ahX + (size_t)((t+1)&1)*32768 + (size_t)xcc*4096;
    float*       ahW = p.ahX + (size_t)(t&1)*32768     + (size_t)xcc*4096;
    const float* dhR = p.dhX + (size_t)((t+1)&1)*32768 + (size_t)xcc*4096;
    float*       dhW = p.dhX + (size_t)(t&1)*32768     + (size_t)xcc*4096;

    // ---- P1: proj(t-1) + att-GEMM + cell ----
    if (t > 0) proj_x(role, xcc, t-1, dhR, ctxX, p);
    gemm_stream<16, 2, 8, 1024, true>(p.awih16, p.awhh16, u0g, b0,
        p.xsT + (size_t)t*8192, ctxX, ahR, Wring, G);
    cell_x(G, u0g, p.abih, p.abhh, cA, hbuf, ahW);
    xbar(p.arr, p.relx, ++ph, xcc, role);

    // ---- P2: energies (+pq) ----
    energies_x(bl, jc, xcc, p, ahW, awXl, awcXl, eXl, scr);
    gbar8(p.arr, p.relg, ++ph, xcc, role);

    // ---- P3: softmax + ctx ----
    smctx_x(bl, jc, xcc, t, p, eXl, awXl, awcXl, ctxX, mem_s, scr);
    xbar(p.arr, p.relx, ++ph, xcc, role);

    // ---- P4: dec-GEMM + cell ----
    gemm_stream<22, 8, 14, 1792, false>(p.dwih16, p.dwhh16, u0g, 0,
        ahW, ctxX, dhR, Wring, G);
    cell_x(G, u0g, p.dbih, p.dbhh, cD, hbuf, dhW);
    xbar(p.arr, p.relx, ++ph, xcc, role);
  }

  // final projection (t = TMEL-1)
  proj_x(role, xcc, TMEL-1,
         p.dhX + (size_t)((TMEL-1)&1)*32768 + (size_t)xcc*4096, ctxX, p);
}

extern "C" void kernel_launch(void* const* d_in, const int* in_sizes, int n_in,
                              void* d_out, int out_size, void* d_ws, size_t ws_size,
                              hipStream_t stream)
{
  const float* memory = (const float*)d_in[0];
  const float* din    = (const float*)d_in[1];
  const float* w1     = (const float*)d_in[3];
  const float* w2     = (const float*)d_in[4];
  const float* awih   = (const float*)d_in[5];
  const float* awhh   = (const float*)d_in[6];
  const float* abih   = (const float*)d_in[7];
  const float* abhh   = (const float*)d_in[8];
  const float* q_w    = (const float*)d_in[9];
  const float* mem_w  = (const float*)d_in[10];
  const float* v_w    = (const float*)d_in[11];
  const float* cw     = (const float*)d_in[12];
  const float* ldw    = (const float*)d_in[13];
  const float* dwih   = (const float*)d_in[14];
  const float* dwhh   = (const float*)d_in[15];
  const float* dbih   = (const float*)d_in[16];
  const float* dbhh   = (const float*)d_in[17];
  const float* pw     = (const float*)d_in[18];
  const float* pb     = (const float*)d_in[19];
  const float* gw     = (const float*)d_in[20];
  const float* gb     = (const float*)d_in[21];
  const int*   mlen   = (const int*)d_in[22];

  float* p = (float*)d_ws;
  float* xsT    = p;              p += 800*256*32;
  __half* awih16 = (__half*)p;    p += 2097152;
  __half* awhh16 = (__half*)p;    p += 2097152;
  __half* dwih16 = (__half*)p;    p += 3670016;
  __half* dwhh16 = (__half*)p;    p += 2097152;
  __half* qw16   = (__half*)p;    p += 65536;
  __half* pm16   = (__half*)p;    p += 819200;
  // ---- zeroed block ----
  float* zs      = p;
  uint32* roleCtr = (uint32*)p;   p += 8;
  uint32* arr    = (uint32*)p;    p += 256*SLOT;
  uint32* relx   = (uint32*)p;    p += 8*SLOT;
  uint32* relg   = (uint32*)p;    p += 32*SLOT;
  float* ahX     = p;             p += 2*8*1024*4;
  float* dhX     = p;             p += 2*8*1024*4;
  float* ctxX    = p;             p += 8*768*4;
  float* awX     = p;             p += 8*4*400;
  float* awcX    = p;             p += 8*4*400;
  float* eX      = p;             p += 8*4*400;
  size_t zcount  = (size_t)(p - zs);
  // ---- end zeroed block ----

  float* out_mel   = (float*)d_out;
  float* out_gate  = out_mel + 32*80*800;
  float* out_align = out_gate + 32*800;

  hipMemsetAsync(zs, 0, zcount*sizeof(float), stream);
  prenet_kernel<<<TMEL, 256, 0, stream>>>(din, w1, w2, xsT);
  pmem_kernel<<<dim3(25,32), 256, 0, stream>>>(memory, mem_w, pm16);
  cvt16_kernel<<<256, 256, 0, stream>>>(q_w, qw16, 128*1024);
  cvt16_kernel<<<2048, 256, 0, stream>>>(awih, awih16, 4096*1024);
  cvt16_kernel<<<2048, 256, 0, stream>>>(awhh, awhh16, 4096*1024);
  cvt16_kernel<<<2048, 256, 0, stream>>>(dwih, dwih16, 4096*1792);
  cvt16_kernel<<<2048, 256, 0, stream>>>(dwhh, dwhh16, 4096*1024);

  DecArgs a;
  a.xsT = xsT;
  a.awih16 = awih16; a.awhh16 = awhh16; a.dwih16 = dwih16; a.dwhh16 = dwhh16;
  a.qw16 = qw16; a.pm16 = pm16;
  a.abih = abih; a.abhh = abhh; a.dbih = dbih; a.dbhh = dbhh;
  a.cw = cw; a.ldw = ldw; a.vw = v_w; a.mlen = mlen;
  a.pw = pw; a.pb = pb; a.gw = gw; a.gb = gb;
  a.memory = memory;
  a.ahX = ahX; a.dhX = dhX; a.ctxX = ctxX; a.awX = awX; a.awcX = awcX; a.eX = eX;
  a.out_mel = out_mel; a.out_gate = out_gate; a.out_align = out_align;
  a.roleCtr = roleCtr; a.arr = arr; a.relx = relx; a.relg = relg;

  decoder_loop<<<NBLK, 256, 0, stream>>>(a);
}